// Round 17
// baseline (423.858 us; speedup 1.0000x reference)
//
#include <hip/hip_runtime.h>
#include <hip/hip_bf16.h>
#include <math.h>

#define ROWS 16384   // B*N = 8*2048

typedef _Float16 f16x8 __attribute__((ext_vector_type(8)));
typedef float f32x4 __attribute__((ext_vector_type(4)));

// ---- workspace offsets (floats); total identical to proven 31,330,304 ----
static const size_t OFF_OVL = 0;            // 16384*512 fp32 overlap
static const size_t OFF_HID = 8388608;      // 16384*128 fp32
static const size_t OFF_N2  = 10485760;     // 16384*8  (n2a)
static const size_t OFF_VG  = 10616832;     // 512*8
static const size_t OFF_MRE = 10620928;     // 65536 (n2b)
static const size_t OFF_MIM = 10686464;     // 65536 (unused)
static const size_t OFF_VWH = 10752000;     // 512*1024 f16 = 262144 fl
static const size_t OFF_VWL = 11014144;     // 262144 fl
static const size_t OFF_BH  = 11276288;     // 1024*3200 f16 = 1638400 fl
static const size_t OFF_BL  = 12914688;     // 1638400 fl
static const size_t OFF_AH  = 14553088;     // 16384*1024 f16 = 8388608 fl; late: WH alias
static const size_t OFF_AL  = 22941696;     // 8388608 fl; late: WL alias
static const size_t WS_FLOATS = 31330304;   // 125.32 MB

__device__ __forceinline__ void gload_lds16(const void* g, void* l) {
  __builtin_amdgcn_global_load_lds((const __attribute__((address_space(1))) void*)g,
                                   (__attribute__((address_space(3))) void*)l, 16, 0, 0);
}

__device__ __forceinline__ void split16(float v, _Float16& hi, _Float16& lo) {
  _Float16 h = (_Float16)v;
  hi = h;
  lo = (_Float16)(v - (float)h);
}

// ---------------- prep: VG[h,s,g] ----------------
__global__ __launch_bounds__(256) void k_prep_vg(const float* __restrict__ vals,
                                                 const float* __restrict__ gw,
                                                 float* __restrict__ VG) {
  int hs = blockIdx.x;
  int h  = hs >> 6;
  int t  = threadIdx.x;
  float acc[8] = {0,0,0,0,0,0,0,0};
  for (int dd = t; dd < 1024; dd += 256) {
    float v = vals[(size_t)hs*1024 + dd];
    const float* g = gw + (size_t)(h*1024 + dd)*8;
    #pragma unroll
    for (int q = 0; q < 8; ++q) acc[q] += v * g[q];
  }
  #pragma unroll
  for (int off = 1; off < 64; off <<= 1)
    #pragma unroll
    for (int q = 0; q < 8; ++q) acc[q] += __shfl_xor(acc[q], off);
  __shared__ float red[4][8];
  if ((t & 63) == 0) {
    #pragma unroll
    for (int q = 0; q < 8; ++q) red[t >> 6][q] = acc[q];
  }
  __syncthreads();
  if (t < 8) VG[(size_t)hs*8 + t] = red[0][t] + red[1][t] + red[2][t] + red[3][t];
}

// ---------------- prep: Wr/Wi/pw1 -> BH/BL fragment tiles directly ----------------
__global__ __launch_bounds__(256) void k_prep_b16(const float* __restrict__ Wr,
                                                  const float* __restrict__ Wi,
                                                  const float* __restrict__ pw1,
                                                  _Float16* __restrict__ BH,
                                                  _Float16* __restrict__ BL) {
  int g = blockIdx.x * 256 + threadIdx.x;   // 128*2176 = 278528 total
  int c  = g % 2176;
  int k0 = g / 2176;                        // 0..127 (8 consecutive k)
  float v[8];
  if (c < 1024) {
    int h = c >> 7, e = c & 127;
    const float* p = Wr + ((size_t)(h << 10) + k0*8) * 128 + e;
    #pragma unroll
    for (int j = 0; j < 8; ++j) v[j] = p[(size_t)j*128];
  } else if (c < 2048) {
    int c2 = c - 1024; int h = c2 >> 7, e = c2 & 127;
    const float* p = Wi + ((size_t)(h << 10) + k0*8) * 128 + e;
    #pragma unroll
    for (int j = 0; j < 8; ++j) v[j] = p[(size_t)j*128];
  } else {
    int q = c - 2048; int h = q >> 4, kk = q & 15;
    const float* p = pw1 + ((size_t)(h << 10) + k0*8) * 16 + kk;
    #pragma unroll
    for (int j = 0; j < 8; ++j) v[j] = p[(size_t)j*16];
  }
  int Bcol = (c < 2048) ? c : 3072 + (c - 2048);
  int nt = Bcol >> 7, c8 = (Bcol >> 4) & 7, c15 = Bcol & 15;
  int kt = k0 >> 2, kg = k0 & 3;
  size_t base = ((size_t)nt*32 + kt)*4096 + c8*512 + kg*128 + c15*8;
  f16x8 hv, lv;
  #pragma unroll
  for (int j = 0; j < 8; ++j) { _Float16 hi, lo; split16(v[j], hi, lo); hv[j] = hi; lv[j] = lo; }
  *(f16x8*)(BH + base) = hv;
  *(f16x8*)(BL + base) = lv;
}

// ---------------- prep: raw mr/mi -> normalize in-LDS -> Aov -> BH/BL tiles (nt 16..23) ----------------
__global__ __launch_bounds__(256) void k_prep_aov16(const float* __restrict__ Wr,
                                                    const float* __restrict__ Wi,
                                                    const float* __restrict__ mr,
                                                    const float* __restrict__ mi,
                                                    _Float16* __restrict__ BH,
                                                    _Float16* __restrict__ BL) {
  int bid = blockIdx.x;          // h(8) x kt64(16) x shalf(2)
  int h   = bid >> 5;
  int kt64 = (bid >> 1) & 15;
  int sh  = bid & 1;
  __shared__ float sRe[32][129];
  __shared__ float sIm[32][129];
  int tid = threadIdx.x;
  int s0 = sh * 32;
  for (int i = tid; i < 32 * 32; i += 256) {
    int s = i >> 5; int e4 = (i & 31) << 2;
    *(float4*)&sRe[s][e4] = *(const float4*)(mr + ((size_t)(h*64 + s0 + s)*128 + e4));
    *(float4*)&sIm[s][e4] = *(const float4*)(mi + ((size_t)(h*64 + s0 + s)*128 + e4));
  }
  __syncthreads();
  {
    int row = tid >> 3, part = tid & 7;
    float ss = 0.f;
    #pragma unroll
    for (int e = 0; e < 16; ++e) {
      float a = sRe[row][part*16 + e], b = sIm[row][part*16 + e];
      ss += a*a + b*b;
    }
    ss += __shfl_xor(ss, 1); ss += __shfl_xor(ss, 2); ss += __shfl_xor(ss, 4);
    float inv = 1.f / fmaxf(sqrtf(ss), 1e-12f);
    #pragma unroll
    for (int e = 0; e < 16; ++e) {
      sRe[row][part*16 + e] *= inv;
      sIm[row][part*16 + e] *= inv;
    }
  }
  __syncthreads();
  int kq = tid >> 5;
  int s  = tid & 31;
  int kbase = kt64*64 + kq*8;
  float aR[8] = {0,0,0,0,0,0,0,0}, aI[8] = {0,0,0,0,0,0,0,0};
  for (int e0 = 0; e0 < 128; e0 += 4) {
    float4 mre = *(float4*)&sRe[s][e0];
    float4 mim = *(float4*)&sIm[s][e0];
    #pragma unroll
    for (int j = 0; j < 8; ++j) {
      const float4 wr = *(const float4*)(Wr + ((size_t)(h*1024 + kbase + j))*128 + e0);
      const float4 wi = *(const float4*)(Wi + ((size_t)(h*1024 + kbase + j))*128 + e0);
      aR[j] += wr.x*mre.x + wr.y*mre.y + wr.z*mre.z + wr.w*mre.w
             + wi.x*mim.x + wi.y*mim.y + wi.z*mim.z + wi.w*mim.w;
      aI[j] += wi.x*mre.x + wi.y*mre.y + wi.z*mre.z + wi.w*mre.w
             - (wr.x*mim.x + wr.y*mim.y + wr.z*mim.z + wr.w*mim.w);
    }
  }
  int kt32 = kbase >> 5;
  int kg   = (kbase >> 3) & 3;
  int coln = s0 + s;
  size_t baseR = ((size_t)(16 + h)*32 + kt32)*4096 + (size_t)(coln >> 4)*512 + kg*128 + (coln & 15)*8;
  size_t baseI = baseR + 4*512;
  f16x8 hR, lR, hI, lI;
  #pragma unroll
  for (int j = 0; j < 8; ++j) {
    _Float16 hi, lo;
    split16(aR[j], hi, lo); hR[j] = hi; lR[j] = lo;
    split16(aI[j], hi, lo); hI[j] = hi; lI[j] = lo;
  }
  *(f16x8*)(BH + baseR) = hR; *(f16x8*)(BL + baseR) = lR;
  *(f16x8*)(BH + baseI) = hI; *(f16x8*)(BL + baseI) = lI;
}

// ---------------- VW = values_flat(512x1024) @ out_w(1024x1024) -> VWH/VWL fragment tiles ----------------
__global__ __launch_bounds__(256) void k_gemm64(const float* __restrict__ A,
                                                const float* __restrict__ B,
                                                int K, int lda, int ldb,
                                                _Float16* __restrict__ dh,
                                                _Float16* __restrict__ dl) {
  __shared__ float As[16][64];
  __shared__ float Bs[16][64];
  int tid = threadIdx.x;
  int tm = tid >> 4, tn = tid & 15;
  float acc[4][4];
  #pragma unroll
  for (int i = 0; i < 4; ++i)
    #pragma unroll
    for (int j = 0; j < 4; ++j) acc[i][j] = 0.f;
  int row0 = blockIdx.y << 6, col0 = blockIdx.x << 6;
  int ar = tid >> 2, ak = (tid & 3) << 2;
  int bkr = tid >> 4, bc = (tid & 15) << 2;
  for (int kt = 0; kt < K; kt += 16) {
    float4 a0 = *(const float4*)(A + (size_t)(row0 + ar)*lda + kt + ak);
    float4 b0 = *(const float4*)(B + (size_t)(kt + bkr)*ldb + col0 + bc);
    __syncthreads();
    As[ak+0][ar] = a0.x; As[ak+1][ar] = a0.y; As[ak+2][ar] = a0.z; As[ak+3][ar] = a0.w;
    *(float4*)&Bs[bkr][bc] = b0;
    __syncthreads();
    #pragma unroll
    for (int k = 0; k < 16; ++k) {
      float af[4], bf[4];
      *(float4*)&af[0] = *(const float4*)&As[k][tm << 2];
      *(float4*)&bf[0] = *(const float4*)&Bs[k][tn << 2];
      #pragma unroll
      for (int i = 0; i < 4; ++i)
        #pragma unroll
        for (int j = 0; j < 4; ++j) acc[i][j] += af[i] * bf[j];
    }
  }
  #pragma unroll
  for (int i = 0; i < 4; ++i) {
    int row = row0 + (tm << 2) + i;            // k-dim 0..511
    int ktl = row >> 5, kg = (row >> 3) & 3, jj = row & 7;
    #pragma unroll
    for (int j = 0; j < 4; ++j) {
      int col = col0 + (tn << 2) + j;          // 0..1023
      int nt = col >> 7, c8 = (col >> 4) & 7, c15 = col & 15;
      size_t base = ((size_t)nt*16 + ktl)*4096 + c8*512 + kg*128 + c15*8 + jj;
      _Float16 hi, lo; split16(acc[i][j], hi, lo);
      dh[base] = hi; dl[base] = lo;
    }
  }
}

// ---------------- convA: row-major fp32 -> hi/lo fragment tiles; float4 reads + 16B f16x8 stores ----------------
__global__ __launch_bounds__(256) void k_convA(const float* __restrict__ src, int lda,
                                               _Float16* __restrict__ dh, _Float16* __restrict__ dl) {
  int mt = blockIdx.x >> 5, kt = blockIdx.x & 31;
  size_t tbase = (size_t)blockIdx.x * 4096;
  #pragma unroll
  for (int it = 0; it < 2; ++it) {
    int p = it*256 + threadIdx.x;      // 0..511 = r8*64 + kg*16 + r15
    int r8 = p >> 6, kg = (p >> 4) & 3, r15 = p & 15;
    int row = mt*128 + r8*16 + r15;
    int col = kt*32 + kg*8;
    const float* s = src + (size_t)row*lda + col;
    float4 v0 = *(const float4*)s;
    float4 v1 = *(const float4*)(s + 4);
    float vv[8] = {v0.x, v0.y, v0.z, v0.w, v1.x, v1.y, v1.z, v1.w};
    f16x8 hv, lv;
    #pragma unroll
    for (int j = 0; j < 8; ++j) { _Float16 hi, lo; split16(vv[j], hi, lo); hv[j] = hi; lv[j] = lo; }
    size_t i = tbase + (size_t)r8*512 + kg*128 + r15*8;
    *(f16x8*)(dh + i) = hv;
    *(f16x8*)(dl + i) = lv;
  }
}

// ---------------- norm GEMM: hi-only, 128x256, counted-vmcnt pipeline; wave owns one head ----------------
__global__ __launch_bounds__(256) void k_qnorm256(const _Float16* __restrict__ Ah,
                                                  const _Float16* __restrict__ Bh,
                                                  float* __restrict__ n2a,
                                                  float* __restrict__ n2b) {
  __shared__ __align__(16) char smem[49152];   // 2 bufs x {A 8K, B0 8K, B1 8K}
  const int id = blockIdx.x;
  const int by = (id & 7) * 16 + ((id >> 3) & 15);
  const int bx = id >> 7;                      // 0..7
  const int tid = threadIdx.x;
  const int wid = tid >> 6, lane = tid & 63;
  const int wr = wid >> 1, wc = wid & 1;
  const char* gA  = (const char*)Ah + (size_t)by * 32 * 8192;
  const char* gB0 = (const char*)Bh + (size_t)(2*bx)     * 32 * 8192;
  const char* gB1 = (const char*)Bh + (size_t)(2*bx + 1) * 32 * 8192;

  f32x4 acc[4][8];
  #pragma unroll
  for (int i = 0; i < 4; ++i)
    #pragma unroll
    for (int j = 0; j < 8; ++j) acc[i][j] = (f32x4){0.f,0.f,0.f,0.f};

  auto stage = [&](int b, int kt) {
    char* dbuf = smem + b * 24576;
    #pragma unroll
    for (int q = 0; q < 6; ++q) {
      int c = wid * 6 + q;                     // 0..23 (wave-uniform)
      const char* s;
      if (c < 8)       s = gA  + (size_t)kt*8192 + c*1024;
      else if (c < 16) s = gB0 + (size_t)kt*8192 + (c-8)*1024;
      else             s = gB1 + (size_t)kt*8192 + (c-16)*1024;
      gload_lds16(s + lane*16, dbuf + c*1024);
    }
  };

  stage(0, 0);
  stage(1, 1);
  asm volatile("s_waitcnt vmcnt(6)" ::: "memory");
  __builtin_amdgcn_s_barrier();
  for (int kt = 0; kt < 32; ++kt) {
    const char* cb = smem + (kt & 1) * 24576;
    const char* bb = cb + 8192 + wc * 8192;
    f16x8 a[4], b[8];
    #pragma unroll
    for (int m = 0; m < 4; ++m) a[m] = *(const f16x8*)(cb + wr*4096 + m*1024 + lane*16);
    #pragma unroll
    for (int n = 0; n < 8; ++n) b[n] = *(const f16x8*)(bb + n*1024 + lane*16);
    asm volatile("s_waitcnt lgkmcnt(0)" ::: "memory");
    __builtin_amdgcn_s_barrier();
    if (kt < 30) stage(kt & 1, kt + 2);
    #pragma unroll
    for (int m = 0; m < 4; ++m)
      #pragma unroll
      for (int n = 0; n < 8; ++n)
        acc[m][n] = __builtin_amdgcn_mfma_f32_16x16x32_f16(a[m], b[n], acc[m][n], 0, 0, 0);
    if (kt < 31) {
      if (kt < 30) asm volatile("s_waitcnt vmcnt(6)" ::: "memory");
      else         asm volatile("s_waitcnt vmcnt(0)" ::: "memory");
      __builtin_amdgcn_s_barrier();
    }
  }

  const int nt = 2*bx + wc;
  float* dst = (nt < 8) ? n2a : n2b;
  const int head = nt & 7;
  #pragma unroll
  for (int m = 0; m < 4; ++m)
    #pragma unroll
    for (int rr = 0; rr < 4; ++rr) {
      float rs = 0.f;
      #pragma unroll
      for (int n = 0; n < 8; ++n) rs += acc[m][n][rr] * acc[m][n][rr];
      rs += __shfl_xor(rs, 1); rs += __shfl_xor(rs, 2);
      rs += __shfl_xor(rs, 4); rs += __shfl_xor(rs, 8);
      if ((lane & 15) == 0) {
        int row = by*128 + wr*64 + m*16 + (lane >> 4)*4 + rr;
        dst[(size_t)row*8 + head] = rs;
      }
    }
}

// ---------------- value GEMM: 3-term, 128x128, 2-barrier double-buffered (round-15 proven) ----------------
__global__ __launch_bounds__(256) void k_qval(const _Float16* __restrict__ Ah,
                                              const _Float16* __restrict__ Al,
                                              const _Float16* __restrict__ Bh,
                                              const _Float16* __restrict__ Bl,
                                              float* __restrict__ OVL,
                                              float* __restrict__ HID) {
  __shared__ __align__(16) char smem[65536];   // 2 bufs x {Ah,Al,Bh,Bl} x 8KB
  const int id = blockIdx.x;
  const int rest = id >> 3;
  const int by = (id & 7) * 16 + (rest & 15);
  const int bx = rest >> 4;                    // 0..8
  const int tid = threadIdx.x;
  const int wid = tid >> 6, lane = tid & 63;
  const int wr = wid >> 1, wc = wid & 1;
  f32x4 acc[4][4];
  #pragma unroll
  for (int i = 0; i < 4; ++i)
    #pragma unroll
    for (int j = 0; j < 4; ++j) acc[i][j] = (f32x4){0.f,0.f,0.f,0.f};

  const char* pAh = (const char*)Ah + (size_t)by*32*8192;
  const char* pAl = (const char*)Al + (size_t)by*32*8192;
  const char* pBh = (const char*)Bh + (size_t)(16 + bx)*32*8192;
  const char* pBl = (const char*)Bl + (size_t)(16 + bx)*32*8192;
  const char* mysrc = (wid == 0) ? pAh : (wid == 1) ? pAl : (wid == 2) ? pBh : pBl;

  auto stage = [&](int b, int kt) {
    const char* s = mysrc + (size_t)kt*8192 + lane*16;
    char* d = smem + b*32768 + wid*8192;
    #pragma unroll
    for (int q = 0; q < 8; ++q)
      gload_lds16(s + q*1024, d + q*1024);
  };

  stage(0, 0);
  asm volatile("s_waitcnt vmcnt(0)" ::: "memory");
  __builtin_amdgcn_s_barrier();
  int cur = 0;
  for (int kt = 0; kt < 32; ++kt) {
    if (kt < 31) stage(cur ^ 1, kt + 1);
    const char* base = smem + cur*32768;
    const char* cAh = base;
    const char* cAl = base + 8192;
    const char* cBh = base + 16384;
    const char* cBl = base + 24576;
    f16x8 a_h[4], a_l[4], b_h[4], b_l[4];
    #pragma unroll
    for (int m = 0; m < 4; ++m) { a_h[m] = *(const f16x8*)(cAh + wr*4096 + m*1024 + lane*16);
                                  a_l[m] = *(const f16x8*)(cAl + wr*4096 + m*1024 + lane*16); }
    #pragma unroll
    for (int n = 0; n < 4; ++n) { b_h[n] = *(const f16x8*)(cBh + wc*4096 + n*1024 + lane*16);
                                  b_l[n] = *(const f16x8*)(cBl + wc*4096 + n*1024 + lane*16); }
    #pragma unroll
    for (int m = 0; m < 4; ++m)
      #pragma unroll
      for (int n = 0; n < 4; ++n) {
        acc[m][n] = __builtin_amdgcn_mfma_f32_16x16x32_f16(a_h[m], b_h[n], acc[m][n], 0, 0, 0);
        acc[m][n] = __builtin_amdgcn_mfma_f32_16x16x32_f16(a_l[m], b_h[n], acc[m][n], 0, 0, 0);
        acc[m][n] = __builtin_amdgcn_mfma_f32_16x16x32_f16(a_h[m], b_l[n], acc[m][n], 0, 0, 0);
      }
    if (kt < 31) {
      asm volatile("s_waitcnt vmcnt(0)" ::: "memory");
      __builtin_amdgcn_s_barrier();
    }
    cur ^= 1;
  }
  __syncthreads();   // all waves done with LDS buffers before epilogue reuse

  if (bx == 8) {
    #pragma unroll
    for (int m = 0; m < 4; ++m)
      #pragma unroll
      for (int n = 0; n < 4; ++n)
        #pragma unroll
        for (int rr = 0; rr < 4; ++rr) {
          int row = by*128 + wr*64 + m*16 + (lane>>4)*4 + rr;
          int col = wc*64 + n*16 + (lane&15);
          HID[(size_t)row*128 + col] = acc[m][n][rr];
        }
  } else {
    float* sOv = (float*)smem;   // [128][68]
    if (wc == 0) {
      #pragma unroll
      for (int m = 0; m < 4; ++m)
        #pragma unroll
        for (int n = 0; n < 4; ++n)
          #pragma unroll
          for (int rr = 0; rr < 4; ++rr) {
            int r128 = wr*64 + m*16 + (lane>>4)*4 + rr;
            int s = n*16 + (lane&15);
            sOv[r128*68 + s] = acc[m][n][rr]*acc[m][n][rr];
          }
    }
    __syncthreads();
    if (wc == 1) {
      #pragma unroll
      for (int m = 0; m < 4; ++m)
        #pragma unroll
        for (int n = 0; n < 4; ++n)
          #pragma unroll
          for (int rr = 0; rr < 4; ++rr) {
            int r128 = wr*64 + m*16 + (lane>>4)*4 + rr;
            int s = n*16 + (lane&15);
            float v = sOv[r128*68 + s] + acc[m][n][rr]*acc[m][n][rr];
            int row = by*128 + r128;
            OVL[(size_t)row*512 + bx*64 + s] = v;
          }
    }
  }
}

// ---------------- final MFMA GEMM: counted-vmcnt pipeline; out = wattn @ VW + out_b ----------------
__global__ __launch_bounds__(256) void k_fin(const _Float16* __restrict__ Ahh,
                                             const _Float16* __restrict__ Alo,
                                             const _Float16* __restrict__ Bhh,
                                             const _Float16* __restrict__ Blo,
                                             const float* __restrict__ bias,
                                             float* __restrict__ out) {
  __shared__ __align__(16) char smem[65536];
  const int id = blockIdx.x;                   // 1024: XCD-partitioned decode
  const int by = (id & 7) * 16 + ((id >> 3) & 15);   // 0..127
  const int bx = id >> 7;                      // 0..7
  const int tid = threadIdx.x;
  const int wid = tid >> 6, lane = tid & 63;
  const int wr = wid >> 1, wc = wid & 1;
  f32x4 acc[4][4];
  #pragma unroll
  for (int i = 0; i < 4; ++i)
    #pragma unroll
    for (int j = 0; j < 4; ++j) acc[i][j] = (f32x4){0.f,0.f,0.f,0.f};
  const char* pAh = (const char*)Ahh + (size_t)by*16*8192;
  const char* pAl = (const char*)Alo + (size_t)by*16*8192;
  const char* pBh = (const char*)Bhh + (size_t)bx*16*8192;
  const char* pBl = (const char*)Blo + (size_t)bx*16*8192;
  const char* mysrc = (wid == 0) ? pAh : (wid == 1) ? pAl : (wid == 2) ? pBh : pBl;

  auto stage = [&](int b, int kt) {
    const char* s = mysrc + (size_t)kt*8192 + lane*16;
    char* d = smem + b*32768 + wid*8192;
    #pragma unroll
    for (int q = 0; q < 8; ++q)
      gload_lds16(s + q*1024, d + q*1024);
  };

  stage(0, 0);
  stage(1, 1);
  asm volatile("s_waitcnt vmcnt(8)" ::: "memory");
  __builtin_amdgcn_s_barrier();
  for (int kt = 0; kt < 16; ++kt) {
    const char* base = smem + (kt & 1)*32768;
    const char* cAh = base;
    const char* cAl = base + 8192;
    const char* cBh = base + 16384;
    const char* cBl = base + 24576;
    f16x8 a_h[4], a_l[4], b_h[4], b_l[4];
    #pragma unroll
    for (int m = 0; m < 4; ++m) { a_h[m] = *(const f16x8*)(cAh + wr*4096 + m*1024 + lane*16);
                                  a_l[m] = *(const f16x8*)(cAl + wr*4096 + m*1024 + lane*16); }
    #pragma unroll
    for (int n = 0; n < 4; ++n) { b_h[n] = *(const f16x8*)(cBh + wc*4096 + n*1024 + lane*16);
                                  b_l[n] = *(const f16x8*)(cBl + wc*4096 + n*1024 + lane*16); }
    asm volatile("s_waitcnt lgkmcnt(0)" ::: "memory");
    __builtin_amdgcn_s_barrier();
    if (kt < 14) stage(kt & 1, kt + 2);
    #pragma unroll
    for (int m = 0; m < 4; ++m)
      #pragma unroll
      for (int n = 0; n < 4; ++n) {
        acc[m][n] = __builtin_amdgcn_mfma_f32_16x16x32_f16(a_h[m], b_h[n], acc[m][n], 0, 0, 0);
        acc[m][n] = __builtin_amdgcn_mfma_f32_16x16x32_f16(a_l[m], b_h[n], acc[m][n], 0, 0, 0);
        acc[m][n] = __builtin_amdgcn_mfma_f32_16x16x32_f16(a_h[m], b_l[n], acc[m][n], 0, 0, 0);
      }
    if (kt < 15) {
      if (kt < 14) asm volatile("s_waitcnt vmcnt(8)" ::: "memory");
      else         asm volatile("s_waitcnt vmcnt(0)" ::: "memory");
      __builtin_amdgcn_s_barrier();
    }
  }
  #pragma unroll
  for (int m = 0; m < 4; ++m)
    #pragma unroll
    for (int n = 0; n < 4; ++n) {
      int col = bx*128 + wc*64 + n*16 + (lane&15);
      float bv = bias[col];
      #pragma unroll
      for (int rr = 0; rr < 4; ++rr) {
        int row = by*128 + wr*64 + m*16 + (lane>>4)*4 + rr;
        out[(size_t)row*1024 + col] = acc[m][n][rr] + bv;
      }
    }
}

// ---------------- per-row attention, wave-per-row (4 rows/block, no barriers/LDS) ----------------
__global__ __launch_bounds__(256) void k_attn(const float* __restrict__ OVL,
                                              const float* __restrict__ HID,
                                              const float* __restrict__ n2a,
                                              const float* __restrict__ n2b,
                                              const float* __restrict__ VG,
                                              const float* __restrict__ pb1,
                                              const float* __restrict__ pw2,
                                              const float* __restrict__ pb2,
                                              const float* __restrict__ gb,
                                              _Float16* __restrict__ WH,
                                              _Float16* __restrict__ WL) {
  const int wid = threadIdx.x >> 6;
  const int lane = threadIdx.x & 63;
  const int r = blockIdx.x * 4 + wid;          // one wave per row
  const int h = lane >> 3;                     // head 0..7 (8 lanes each)
  const int sub = lane & 7;                    // 8 s-values per lane
  const float* ovp = OVL + (size_t)r*512 + h*64 + sub*8;
  float4 o0 = *(const float4*)ovp;
  float4 o1 = *(const float4*)(ovp + 4);
  float ov[8] = {o0.x, o0.y, o0.z, o0.w, o1.x, o1.y, o1.z, o1.w};
  float z = 0.f;
  #pragma unroll
  for (int t = 0; t < 2; ++t) {
    int kk = sub*2 + t;
    float x = HID[(size_t)r*128 + h*16 + kk] + pb1[h*16 + kk];
    float sg = 1.f / (1.f + expf(-x));
    z += x * sg * pw2[h*16 + kk];
  }
  z += __shfl_xor(z, 1); z += __shfl_xor(z, 2); z += __shfl_xor(z, 4);
  z += pb2[h];
  float p = 0.95f / (1.f + expf(-z));
  float nn = n2a[(size_t)r*8 + h] + n2b[(size_t)r*8 + h];
  float inv_n2 = 1.f / fmaxf(nn, 1e-24f);
  float base = (1.f - p) * 0.0078125f;   // (1-p)/128
  float rw[8];
  float rsum = 0.f;
  #pragma unroll
  for (int q = 0; q < 8; ++q) { rw[q] = p * (ov[q] * inv_n2) + base; rsum += rw[q]; }
  rsum += __shfl_xor(rsum, 1); rsum += __shfl_xor(rsum, 2); rsum += __shfl_xor(rsum, 4);
  float inv_den = 1.f / (rsum + 1e-8f);
  float a[8];
  #pragma unroll
  for (int q = 0; q < 8; ++q) a[q] = rw[q] * inv_den;
  float lg[8] = {0,0,0,0,0,0,0,0};
  const float* vgp = VG + (size_t)(h*64 + sub*8) * 8;
  #pragma unroll
  for (int q = 0; q < 8; ++q)
    #pragma unroll
    for (int g = 0; g < 8; ++g) lg[g] += a[q] * vgp[q*8 + g];
  #pragma unroll
  for (int off = 1; off < 64; off <<= 1)
    #pragma unroll
    for (int g = 0; g < 8; ++g) lg[g] += __shfl_xor(lg[g], off);
  float lt[8];
  #pragma unroll
  for (int g = 0; g < 8; ++g) lt[g] = lg[g] + gb[g];
  float mx = lt[0];
  #pragma unroll
  for (int g = 1; g < 8; ++g) mx = fmaxf(mx, lt[g]);
  float den = 0.f;
  #pragma unroll
  for (int g = 0; g < 8; ++g) den += expf(lt[g] - mx);
  float gate = expf(lt[h] - mx) / den;
  int mt = r >> 7, r8 = (r >> 4) & 7, r15 = r & 15;
  size_t basek = ((size_t)mt*16 + h*2 + (sub >> 2)) * 4096
               + (size_t)r8*512 + (size_t)(sub & 3)*128 + (size_t)r15*8;
  f16x8 hv, lv;
  #pragma unroll
  for (int q = 0; q < 8; ++q) {
    _Float16 hi, lo;
    split16(a[q] * gate, hi, lo);
    hv[q] = hi; lv[q] = lo;
  }
  *(f16x8*)(WH + basek) = hv;
  *(f16x8*)(WL + basek) = lv;
}

extern "C" void kernel_launch(void* const* d_in, const int* in_sizes, int n_in,
                              void* d_out, int out_size, void* d_ws, size_t ws_size,
                              hipStream_t stream) {
  const float* h_   = (const float*)d_in[0];
  const float* Wr   = (const float*)d_in[1];
  const float* Wi   = (const float*)d_in[2];
  const float* pw1  = (const float*)d_in[3];
  const float* pb1  = (const float*)d_in[4];
  const float* pw2  = (const float*)d_in[5];
  const float* pb2  = (const float*)d_in[6];
  const float* mr   = (const float*)d_in[7];
  const float* mi   = (const float*)d_in[8];
  const float* vals = (const float*)d_in[9];
  const float* gw   = (const float*)d_in[10];
  const float* gb   = (const float*)d_in[11];
  const float* ow   = (const float*)d_in[12];
  const float* ob   = (const float*)d_in[13];

  if (ws_size < WS_FLOATS * sizeof(float)) return;

  float* ws   = (float*)d_ws;
  float* OVL  = ws + OFF_OVL;
  float* HID  = ws + OFF_HID;
  float* n2a  = ws + OFF_N2;
  float* n2b  = ws + OFF_MRE;
  float* VG   = ws + OFF_VG;
  _Float16* VWH = (_Float16*)(ws + OFF_VWH);
  _Float16* VWL = (_Float16*)(ws + OFF_VWL);
  _Float16* BH  = (_Float16*)(ws + OFF_BH);
  _Float16* BL  = (_Float16*)(ws + OFF_BL);
  _Float16* AH  = (_Float16*)(ws + OFF_AH);
  _Float16* AL  = (_Float16*)(ws + OFF_AL);
  _Float16* WH  = (_Float16*)(ws + OFF_AH);  // alias: A dead after k_qval
  _Float16* WL  = (_Float16*)(ws + OFF_AL);

  k_prep_vg<<<512, 256, 0, stream>>>(vals, gw, VG);
  k_prep_b16<<<1088, 256, 0, stream>>>(Wr, Wi, pw1, BH, BL);
  k_prep_aov16<<<256, 256, 0, stream>>>(Wr, Wi, mr, mi, BH, BL);
  k_gemm64<<<dim3(16, 8), 256, 0, stream>>>(vals, ow, 1024, 1024, 1024, VWH, VWL);
  k_convA<<<4096, 256, 0, stream>>>(h_, 1024, AH, AL);
  k_qnorm256<<<1024, 256, 0, stream>>>(AH, BH, n2a, n2b);
  k_qval<<<1152, 256, 0, stream>>>(AH, AL, BH, BL, OVL, HID);
  k_attn<<<4096, 256, 0, stream>>>(OVL, HID, n2a, n2b, VG, pb1, pw2, pb2, gb, WH, WL);
  k_fin<<<1024, 256, 0, stream>>>(WH, WL, VWH, VWL, ob, (float*)d_out);
}

// Round 18
// 381.142 us; speedup vs baseline: 1.1121x; 1.1121x over previous
//
#include <hip/hip_runtime.h>
#include <hip/hip_bf16.h>
#include <math.h>

#define ROWS 16384   // B*N = 8*2048

typedef _Float16 f16x8 __attribute__((ext_vector_type(8)));
typedef float f32x4 __attribute__((ext_vector_type(4)));

// ---- workspace offsets (floats); total identical to proven 31,330,304 ----
static const size_t OFF_OVL = 0;            // 16384*512 fp32 overlap
static const size_t OFF_HID = 8388608;      // 16384*128 fp32
static const size_t OFF_N2  = 10485760;     // 16384*8  (n2a)
static const size_t OFF_VG  = 10616832;     // 512*8
static const size_t OFF_MRE = 10620928;     // 65536 (n2b)
static const size_t OFF_MIM = 10686464;     // 65536 (unused)
static const size_t OFF_VWH = 10752000;     // 512*1024 f16 = 262144 fl
static const size_t OFF_VWL = 11014144;     // 262144 fl
static const size_t OFF_BH  = 11276288;     // 1024*3200 f16 = 1638400 fl
static const size_t OFF_BL  = 12914688;     // 1638400 fl
static const size_t OFF_AH  = 14553088;     // 16384*1024 f16 = 8388608 fl; late: WH alias
static const size_t OFF_AL  = 22941696;     // 8388608 fl; late: WL alias
static const size_t WS_FLOATS = 31330304;   // 125.32 MB

__device__ __forceinline__ void gload_lds16(const void* g, void* l) {
  __builtin_amdgcn_global_load_lds((const __attribute__((address_space(1))) void*)g,
                                   (__attribute__((address_space(3))) void*)l, 16, 0, 0);
}

__device__ __forceinline__ void split16(float v, _Float16& hi, _Float16& lo) {
  _Float16 h = (_Float16)v;
  hi = h;
  lo = (_Float16)(v - (float)h);
}

// ---------------- merged prep: vg(512) | b16(1088) | aov16(256) | gemm64(128) | convA(4096) ----------------
__global__ __launch_bounds__(256) void k_prep_all(const float* __restrict__ h_,
                                                  const float* __restrict__ Wr,
                                                  const float* __restrict__ Wi,
                                                  const float* __restrict__ pw1,
                                                  const float* __restrict__ mr,
                                                  const float* __restrict__ mi,
                                                  const float* __restrict__ vals,
                                                  const float* __restrict__ gw,
                                                  const float* __restrict__ ow,
                                                  float* __restrict__ VG,
                                                  _Float16* __restrict__ BH,
                                                  _Float16* __restrict__ BL,
                                                  _Float16* __restrict__ VWH,
                                                  _Float16* __restrict__ VWL,
                                                  _Float16* __restrict__ AH,
                                                  _Float16* __restrict__ AL) {
  __shared__ __align__(16) char pbuf[33024];
  const int b = blockIdx.x;
  const int tid = threadIdx.x;

  if (b < 512) {
    // ---- prep_vg: VG[h,s,g] ----
    int hs = b;
    int h  = hs >> 6;
    float acc[8] = {0,0,0,0,0,0,0,0};
    for (int dd = tid; dd < 1024; dd += 256) {
      float v = vals[(size_t)hs*1024 + dd];
      const float* g = gw + (size_t)(h*1024 + dd)*8;
      #pragma unroll
      for (int q = 0; q < 8; ++q) acc[q] += v * g[q];
    }
    #pragma unroll
    for (int off = 1; off < 64; off <<= 1)
      #pragma unroll
      for (int q = 0; q < 8; ++q) acc[q] += __shfl_xor(acc[q], off);
    float* red = (float*)pbuf;   // [4][8]
    if ((tid & 63) == 0) {
      #pragma unroll
      for (int q = 0; q < 8; ++q) red[(tid >> 6)*8 + q] = acc[q];
    }
    __syncthreads();
    if (tid < 8) VG[(size_t)hs*8 + tid] = red[tid] + red[8 + tid] + red[16 + tid] + red[24 + tid];

  } else if (b < 1600) {
    // ---- prep_b16: Wr/Wi/pw1 -> BH/BL fragment tiles ----
    int g = (b - 512) * 256 + tid;   // 128*2176 = 278528 total
    int c  = g % 2176;
    int k0 = g / 2176;
    float v[8];
    if (c < 1024) {
      int h = c >> 7, e = c & 127;
      const float* p = Wr + ((size_t)(h << 10) + k0*8) * 128 + e;
      #pragma unroll
      for (int j = 0; j < 8; ++j) v[j] = p[(size_t)j*128];
    } else if (c < 2048) {
      int c2 = c - 1024; int h = c2 >> 7, e = c2 & 127;
      const float* p = Wi + ((size_t)(h << 10) + k0*8) * 128 + e;
      #pragma unroll
      for (int j = 0; j < 8; ++j) v[j] = p[(size_t)j*128];
    } else {
      int q = c - 2048; int h = q >> 4, kk = q & 15;
      const float* p = pw1 + ((size_t)(h << 10) + k0*8) * 16 + kk;
      #pragma unroll
      for (int j = 0; j < 8; ++j) v[j] = p[(size_t)j*16];
    }
    int Bcol = (c < 2048) ? c : 3072 + (c - 2048);
    int nt = Bcol >> 7, c8 = (Bcol >> 4) & 7, c15 = Bcol & 15;
    int kt = k0 >> 2, kg = k0 & 3;
    size_t base = ((size_t)nt*32 + kt)*4096 + c8*512 + kg*128 + c15*8;
    f16x8 hv, lv;
    #pragma unroll
    for (int j = 0; j < 8; ++j) { _Float16 hi, lo; split16(v[j], hi, lo); hv[j] = hi; lv[j] = lo; }
    *(f16x8*)(BH + base) = hv;
    *(f16x8*)(BL + base) = lv;

  } else if (b < 1856) {
    // ---- prep_aov16: normalize mr/mi in-LDS -> Aov -> BH/BL (nt 16..23) ----
    int bid = b - 1600;            // h(8) x kt64(16) x shalf(2)
    int h   = bid >> 5;
    int kt64 = (bid >> 1) & 15;
    int sh  = bid & 1;
    float (*sRe)[129] = (float(*)[129])pbuf;
    float (*sIm)[129] = (float(*)[129])(pbuf + 16512);
    int s0 = sh * 32;
    for (int i = tid; i < 32 * 32; i += 256) {
      int s = i >> 5; int e4 = (i & 31) << 2;
      *(float4*)&sRe[s][e4] = *(const float4*)(mr + ((size_t)(h*64 + s0 + s)*128 + e4));
      *(float4*)&sIm[s][e4] = *(const float4*)(mi + ((size_t)(h*64 + s0 + s)*128 + e4));
    }
    __syncthreads();
    {
      int row = tid >> 3, part = tid & 7;
      float ss = 0.f;
      #pragma unroll
      for (int e = 0; e < 16; ++e) {
        float a = sRe[row][part*16 + e], bb = sIm[row][part*16 + e];
        ss += a*a + bb*bb;
      }
      ss += __shfl_xor(ss, 1); ss += __shfl_xor(ss, 2); ss += __shfl_xor(ss, 4);
      float inv = 1.f / fmaxf(sqrtf(ss), 1e-12f);
      #pragma unroll
      for (int e = 0; e < 16; ++e) {
        sRe[row][part*16 + e] *= inv;
        sIm[row][part*16 + e] *= inv;
      }
    }
    __syncthreads();
    int kq = tid >> 5;
    int s  = tid & 31;
    int kbase = kt64*64 + kq*8;
    float aR[8] = {0,0,0,0,0,0,0,0}, aI[8] = {0,0,0,0,0,0,0,0};
    for (int e0 = 0; e0 < 128; e0 += 4) {
      float4 mre = *(float4*)&sRe[s][e0];
      float4 mim = *(float4*)&sIm[s][e0];
      #pragma unroll
      for (int j = 0; j < 8; ++j) {
        const float4 wr = *(const float4*)(Wr + ((size_t)(h*1024 + kbase + j))*128 + e0);
        const float4 wi = *(const float4*)(Wi + ((size_t)(h*1024 + kbase + j))*128 + e0);
        aR[j] += wr.x*mre.x + wr.y*mre.y + wr.z*mre.z + wr.w*mre.w
               + wi.x*mim.x + wi.y*mim.y + wi.z*mim.z + wi.w*mim.w;
        aI[j] += wi.x*mre.x + wi.y*mre.y + wi.z*mre.z + wi.w*mre.w
               - (wr.x*mim.x + wr.y*mim.y + wr.z*mim.z + wr.w*mim.w);
      }
    }
    int kt32 = kbase >> 5;
    int kg   = (kbase >> 3) & 3;
    int coln = s0 + s;
    size_t baseR = ((size_t)(16 + h)*32 + kt32)*4096 + (size_t)(coln >> 4)*512 + kg*128 + (coln & 15)*8;
    size_t baseI = baseR + 4*512;
    f16x8 hR, lR, hI, lI;
    #pragma unroll
    for (int j = 0; j < 8; ++j) {
      _Float16 hi, lo;
      split16(aR[j], hi, lo); hR[j] = hi; lR[j] = lo;
      split16(aI[j], hi, lo); hI[j] = hi; lI[j] = lo;
    }
    *(f16x8*)(BH + baseR) = hR; *(f16x8*)(BL + baseR) = lR;
    *(f16x8*)(BH + baseI) = hI; *(f16x8*)(BL + baseI) = lI;

  } else if (b < 1984) {
    // ---- gemm64: VW = vals(512x1024) @ ow(1024x1024) -> VWH/VWL fragment tiles ----
    int sub = b - 1856;                 // 0..127
    int col0 = (sub & 15) << 6, row0 = (sub >> 4) << 6;
    float (*As)[64] = (float(*)[64])pbuf;
    float (*Bs)[64] = (float(*)[64])(pbuf + 4096);
    int tm = tid >> 4, tn = tid & 15;
    float acc[4][4];
    #pragma unroll
    for (int i = 0; i < 4; ++i)
      #pragma unroll
      for (int j = 0; j < 4; ++j) acc[i][j] = 0.f;
    int ar = tid >> 2, ak = (tid & 3) << 2;
    int bkr = tid >> 4, bc = (tid & 15) << 2;
    for (int kt = 0; kt < 1024; kt += 16) {
      float4 a0 = *(const float4*)(vals + (size_t)(row0 + ar)*1024 + kt + ak);
      float4 b0 = *(const float4*)(ow + (size_t)(kt + bkr)*1024 + col0 + bc);
      __syncthreads();
      As[ak+0][ar] = a0.x; As[ak+1][ar] = a0.y; As[ak+2][ar] = a0.z; As[ak+3][ar] = a0.w;
      *(float4*)&Bs[bkr][bc] = b0;
      __syncthreads();
      #pragma unroll
      for (int k = 0; k < 16; ++k) {
        float af[4], bf[4];
        *(float4*)&af[0] = *(const float4*)&As[k][tm << 2];
        *(float4*)&bf[0] = *(const float4*)&Bs[k][tn << 2];
        #pragma unroll
        for (int i = 0; i < 4; ++i)
          #pragma unroll
          for (int j = 0; j < 4; ++j) acc[i][j] += af[i] * bf[j];
      }
    }
    #pragma unroll
    for (int i = 0; i < 4; ++i) {
      int row = row0 + (tm << 2) + i;            // k-dim 0..511
      int ktl = row >> 5, kg = (row >> 3) & 3, jj = row & 7;
      #pragma unroll
      for (int j = 0; j < 4; ++j) {
        int col = col0 + (tn << 2) + j;          // 0..1023
        int nt = col >> 7, c8 = (col >> 4) & 7, c15 = col & 15;
        size_t base = ((size_t)nt*16 + ktl)*4096 + c8*512 + kg*128 + c15*8 + jj;
        _Float16 hi, lo; split16(acc[i][j], hi, lo);
        VWH[base] = hi; VWL[base] = lo;
      }
    }

  } else {
    // ---- convA: h row-major -> AH/AL fragment tiles ----
    int cb = b - 1984;                  // 0..4095
    int mt = cb >> 5, kt = cb & 31;
    size_t tbase = (size_t)cb * 4096;
    #pragma unroll
    for (int it = 0; it < 2; ++it) {
      int p = it*256 + tid;            // 0..511 = r8*64 + kg*16 + r15
      int r8 = p >> 6, kg = (p >> 4) & 3, r15 = p & 15;
      int row = mt*128 + r8*16 + r15;
      int col = kt*32 + kg*8;
      const float* s = h_ + (size_t)row*1024 + col;
      float4 v0 = *(const float4*)s;
      float4 v1 = *(const float4*)(s + 4);
      float vv[8] = {v0.x, v0.y, v0.z, v0.w, v1.x, v1.y, v1.z, v1.w};
      f16x8 hv, lv;
      #pragma unroll
      for (int j = 0; j < 8; ++j) { _Float16 hi, lo; split16(vv[j], hi, lo); hv[j] = hi; lv[j] = lo; }
      size_t i = tbase + (size_t)r8*512 + kg*128 + r15*8;
      *(f16x8*)(AH + i) = hv;
      *(f16x8*)(AL + i) = lv;
    }
  }
}

// ---------------- norm GEMM: hi-only, 128x256, counted-vmcnt pipeline; wave owns one head ----------------
__global__ __launch_bounds__(256) void k_qnorm256(const _Float16* __restrict__ Ah,
                                                  const _Float16* __restrict__ Bh,
                                                  float* __restrict__ n2a,
                                                  float* __restrict__ n2b) {
  __shared__ __align__(16) char smem[49152];   // 2 bufs x {A 8K, B0 8K, B1 8K}
  const int id = blockIdx.x;
  const int by = (id & 7) * 16 + ((id >> 3) & 15);
  const int bx = id >> 7;                      // 0..7
  const int tid = threadIdx.x;
  const int wid = tid >> 6, lane = tid & 63;
  const int wr = wid >> 1, wc = wid & 1;
  const char* gA  = (const char*)Ah + (size_t)by * 32 * 8192;
  const char* gB0 = (const char*)Bh + (size_t)(2*bx)     * 32 * 8192;
  const char* gB1 = (const char*)Bh + (size_t)(2*bx + 1) * 32 * 8192;

  f32x4 acc[4][8];
  #pragma unroll
  for (int i = 0; i < 4; ++i)
    #pragma unroll
    for (int j = 0; j < 8; ++j) acc[i][j] = (f32x4){0.f,0.f,0.f,0.f};

  auto stage = [&](int b, int kt) {
    char* dbuf = smem + b * 24576;
    #pragma unroll
    for (int q = 0; q < 6; ++q) {
      int c = wid * 6 + q;                     // 0..23 (wave-uniform)
      const char* s;
      if (c < 8)       s = gA  + (size_t)kt*8192 + c*1024;
      else if (c < 16) s = gB0 + (size_t)kt*8192 + (c-8)*1024;
      else             s = gB1 + (size_t)kt*8192 + (c-16)*1024;
      gload_lds16(s + lane*16, dbuf + c*1024);
    }
  };

  stage(0, 0);
  stage(1, 1);
  asm volatile("s_waitcnt vmcnt(6)" ::: "memory");
  __builtin_amdgcn_s_barrier();
  for (int kt = 0; kt < 32; ++kt) {
    const char* cb = smem + (kt & 1) * 24576;
    const char* bb = cb + 8192 + wc * 8192;
    f16x8 a[4], b[8];
    #pragma unroll
    for (int m = 0; m < 4; ++m) a[m] = *(const f16x8*)(cb + wr*4096 + m*1024 + lane*16);
    #pragma unroll
    for (int n = 0; n < 8; ++n) b[n] = *(const f16x8*)(bb + n*1024 + lane*16);
    asm volatile("s_waitcnt lgkmcnt(0)" ::: "memory");
    __builtin_amdgcn_s_barrier();
    if (kt < 30) stage(kt & 1, kt + 2);
    #pragma unroll
    for (int m = 0; m < 4; ++m)
      #pragma unroll
      for (int n = 0; n < 8; ++n)
        acc[m][n] = __builtin_amdgcn_mfma_f32_16x16x32_f16(a[m], b[n], acc[m][n], 0, 0, 0);
    if (kt < 31) {
      if (kt < 30) asm volatile("s_waitcnt vmcnt(6)" ::: "memory");
      else         asm volatile("s_waitcnt vmcnt(0)" ::: "memory");
      __builtin_amdgcn_s_barrier();
    }
  }

  const int nt = 2*bx + wc;
  float* dst = (nt < 8) ? n2a : n2b;
  const int head = nt & 7;
  #pragma unroll
  for (int m = 0; m < 4; ++m)
    #pragma unroll
    for (int rr = 0; rr < 4; ++rr) {
      float rs = 0.f;
      #pragma unroll
      for (int n = 0; n < 8; ++n) rs += acc[m][n][rr] * acc[m][n][rr];
      rs += __shfl_xor(rs, 1); rs += __shfl_xor(rs, 2);
      rs += __shfl_xor(rs, 4); rs += __shfl_xor(rs, 8);
      if ((lane & 15) == 0) {
        int row = by*128 + wr*64 + m*16 + (lane >> 4)*4 + rr;
        dst[(size_t)row*8 + head] = rs;
      }
    }
}

// ---------------- value GEMM: 3-term, 128x128, 2-barrier double-buffered (proven) ----------------
__global__ __launch_bounds__(256) void k_qval(const _Float16* __restrict__ Ah,
                                              const _Float16* __restrict__ Al,
                                              const _Float16* __restrict__ Bh,
                                              const _Float16* __restrict__ Bl,
                                              float* __restrict__ OVL,
                                              float* __restrict__ HID) {
  __shared__ __align__(16) char smem[65536];   // 2 bufs x {Ah,Al,Bh,Bl} x 8KB
  const int id = blockIdx.x;
  const int rest = id >> 3;
  const int by = (id & 7) * 16 + (rest & 15);
  const int bx = rest >> 4;                    // 0..8
  const int tid = threadIdx.x;
  const int wid = tid >> 6, lane = tid & 63;
  const int wr = wid >> 1, wc = wid & 1;
  f32x4 acc[4][4];
  #pragma unroll
  for (int i = 0; i < 4; ++i)
    #pragma unroll
    for (int j = 0; j < 4; ++j) acc[i][j] = (f32x4){0.f,0.f,0.f,0.f};

  const char* pAh = (const char*)Ah + (size_t)by*32*8192;
  const char* pAl = (const char*)Al + (size_t)by*32*8192;
  const char* pBh = (const char*)Bh + (size_t)(16 + bx)*32*8192;
  const char* pBl = (const char*)Bl + (size_t)(16 + bx)*32*8192;
  const char* mysrc = (wid == 0) ? pAh : (wid == 1) ? pAl : (wid == 2) ? pBh : pBl;

  auto stage = [&](int b, int kt) {
    const char* s = mysrc + (size_t)kt*8192 + lane*16;
    char* d = smem + b*32768 + wid*8192;
    #pragma unroll
    for (int q = 0; q < 8; ++q)
      gload_lds16(s + q*1024, d + q*1024);
  };

  stage(0, 0);
  asm volatile("s_waitcnt vmcnt(0)" ::: "memory");
  __builtin_amdgcn_s_barrier();
  int cur = 0;
  for (int kt = 0; kt < 32; ++kt) {
    if (kt < 31) stage(cur ^ 1, kt + 1);
    const char* base = smem + cur*32768;
    const char* cAh = base;
    const char* cAl = base + 8192;
    const char* cBh = base + 16384;
    const char* cBl = base + 24576;
    f16x8 a_h[4], a_l[4], b_h[4], b_l[4];
    #pragma unroll
    for (int m = 0; m < 4; ++m) { a_h[m] = *(const f16x8*)(cAh + wr*4096 + m*1024 + lane*16);
                                  a_l[m] = *(const f16x8*)(cAl + wr*4096 + m*1024 + lane*16); }
    #pragma unroll
    for (int n = 0; n < 4; ++n) { b_h[n] = *(const f16x8*)(cBh + wc*4096 + n*1024 + lane*16);
                                  b_l[n] = *(const f16x8*)(cBl + wc*4096 + n*1024 + lane*16); }
    #pragma unroll
    for (int m = 0; m < 4; ++m)
      #pragma unroll
      for (int n = 0; n < 4; ++n) {
        acc[m][n] = __builtin_amdgcn_mfma_f32_16x16x32_f16(a_h[m], b_h[n], acc[m][n], 0, 0, 0);
        acc[m][n] = __builtin_amdgcn_mfma_f32_16x16x32_f16(a_l[m], b_h[n], acc[m][n], 0, 0, 0);
        acc[m][n] = __builtin_amdgcn_mfma_f32_16x16x32_f16(a_h[m], b_l[n], acc[m][n], 0, 0, 0);
      }
    if (kt < 31) {
      asm volatile("s_waitcnt vmcnt(0)" ::: "memory");
      __builtin_amdgcn_s_barrier();
    }
    cur ^= 1;
  }
  __syncthreads();   // all waves done with LDS buffers before epilogue reuse

  if (bx == 8) {
    #pragma unroll
    for (int m = 0; m < 4; ++m)
      #pragma unroll
      for (int n = 0; n < 4; ++n)
        #pragma unroll
        for (int rr = 0; rr < 4; ++rr) {
          int row = by*128 + wr*64 + m*16 + (lane>>4)*4 + rr;
          int col = wc*64 + n*16 + (lane&15);
          HID[(size_t)row*128 + col] = acc[m][n][rr];
        }
  } else {
    float* sOv = (float*)smem;   // [128][68]
    if (wc == 0) {
      #pragma unroll
      for (int m = 0; m < 4; ++m)
        #pragma unroll
        for (int n = 0; n < 4; ++n)
          #pragma unroll
          for (int rr = 0; rr < 4; ++rr) {
            int r128 = wr*64 + m*16 + (lane>>4)*4 + rr;
            int s = n*16 + (lane&15);
            sOv[r128*68 + s] = acc[m][n][rr]*acc[m][n][rr];
          }
    }
    __syncthreads();
    if (wc == 1) {
      #pragma unroll
      for (int m = 0; m < 4; ++m)
        #pragma unroll
        for (int n = 0; n < 4; ++n)
          #pragma unroll
          for (int rr = 0; rr < 4; ++rr) {
            int r128 = wr*64 + m*16 + (lane>>4)*4 + rr;
            int s = n*16 + (lane&15);
            float v = sOv[r128*68 + s] + acc[m][n][rr]*acc[m][n][rr];
            int row = by*128 + r128;
            OVL[(size_t)row*512 + bx*64 + s] = v;
          }
    }
  }
}

// ---------------- final MFMA GEMM: counted-vmcnt pipeline; out = wattn @ VW + out_b ----------------
__global__ __launch_bounds__(256) void k_fin(const _Float16* __restrict__ Ahh,
                                             const _Float16* __restrict__ Alo,
                                             const _Float16* __restrict__ Bhh,
                                             const _Float16* __restrict__ Blo,
                                             const float* __restrict__ bias,
                                             float* __restrict__ out) {
  __shared__ __align__(16) char smem[65536];
  const int id = blockIdx.x;                   // 1024: XCD-partitioned decode
  const int by = (id & 7) * 16 + ((id >> 3) & 15);   // 0..127
  const int bx = id >> 7;                      // 0..7
  const int tid = threadIdx.x;
  const int wid = tid >> 6, lane = tid & 63;
  const int wr = wid >> 1, wc = wid & 1;
  f32x4 acc[4][4];
  #pragma unroll
  for (int i = 0; i < 4; ++i)
    #pragma unroll
    for (int j = 0; j < 4; ++j) acc[i][j] = (f32x4){0.f,0.f,0.f,0.f};
  const char* pAh = (const char*)Ahh + (size_t)by*16*8192;
  const char* pAl = (const char*)Alo + (size_t)by*16*8192;
  const char* pBh = (const char*)Bhh + (size_t)bx*16*8192;
  const char* pBl = (const char*)Blo + (size_t)bx*16*8192;
  const char* mysrc = (wid == 0) ? pAh : (wid == 1) ? pAl : (wid == 2) ? pBh : pBl;

  auto stage = [&](int b, int kt) {
    const char* s = mysrc + (size_t)kt*8192 + lane*16;
    char* d = smem + b*32768 + wid*8192;
    #pragma unroll
    for (int q = 0; q < 8; ++q)
      gload_lds16(s + q*1024, d + q*1024);
  };

  stage(0, 0);
  stage(1, 1);
  asm volatile("s_waitcnt vmcnt(8)" ::: "memory");
  __builtin_amdgcn_s_barrier();
  for (int kt = 0; kt < 16; ++kt) {
    const char* base = smem + (kt & 1)*32768;
    const char* cAh = base;
    const char* cAl = base + 8192;
    const char* cBh = base + 16384;
    const char* cBl = base + 24576;
    f16x8 a_h[4], a_l[4], b_h[4], b_l[4];
    #pragma unroll
    for (int m = 0; m < 4; ++m) { a_h[m] = *(const f16x8*)(cAh + wr*4096 + m*1024 + lane*16);
                                  a_l[m] = *(const f16x8*)(cAl + wr*4096 + m*1024 + lane*16); }
    #pragma unroll
    for (int n = 0; n < 4; ++n) { b_h[n] = *(const f16x8*)(cBh + wc*4096 + n*1024 + lane*16);
                                  b_l[n] = *(const f16x8*)(cBl + wc*4096 + n*1024 + lane*16); }
    asm volatile("s_waitcnt lgkmcnt(0)" ::: "memory");
    __builtin_amdgcn_s_barrier();
    if (kt < 14) stage(kt & 1, kt + 2);
    #pragma unroll
    for (int m = 0; m < 4; ++m)
      #pragma unroll
      for (int n = 0; n < 4; ++n) {
        acc[m][n] = __builtin_amdgcn_mfma_f32_16x16x32_f16(a_h[m], b_h[n], acc[m][n], 0, 0, 0);
        acc[m][n] = __builtin_amdgcn_mfma_f32_16x16x32_f16(a_l[m], b_h[n], acc[m][n], 0, 0, 0);
        acc[m][n] = __builtin_amdgcn_mfma_f32_16x16x32_f16(a_h[m], b_l[n], acc[m][n], 0, 0, 0);
      }
    if (kt < 15) {
      if (kt < 14) asm volatile("s_waitcnt vmcnt(8)" ::: "memory");
      else         asm volatile("s_waitcnt vmcnt(0)" ::: "memory");
      __builtin_amdgcn_s_barrier();
    }
  }
  #pragma unroll
  for (int m = 0; m < 4; ++m)
    #pragma unroll
    for (int n = 0; n < 4; ++n) {
      int col = bx*128 + wc*64 + n*16 + (lane&15);
      float bv = bias[col];
      #pragma unroll
      for (int rr = 0; rr < 4; ++rr) {
        int row = by*128 + wr*64 + m*16 + (lane>>4)*4 + rr;
        out[(size_t)row*1024 + col] = acc[m][n][rr] + bv;
      }
    }
}

// ---------------- per-row attention, wave-per-row (4 rows/block, no barriers/LDS) ----------------
__global__ __launch_bounds__(256) void k_attn(const float* __restrict__ OVL,
                                              const float* __restrict__ HID,
                                              const float* __restrict__ n2a,
                                              const float* __restrict__ n2b,
                                              const float* __restrict__ VG,
                                              const float* __restrict__ pb1,
                                              const float* __restrict__ pw2,
                                              const float* __restrict__ pb2,
                                              const float* __restrict__ gb,
                                              _Float16* __restrict__ WH,
                                              _Float16* __restrict__ WL) {
  const int wid = threadIdx.x >> 6;
  const int lane = threadIdx.x & 63;
  const int r = blockIdx.x * 4 + wid;          // one wave per row
  const int h = lane >> 3;                     // head 0..7 (8 lanes each)
  const int sub = lane & 7;                    // 8 s-values per lane
  const float* ovp = OVL + (size_t)r*512 + h*64 + sub*8;
  float4 o0 = *(const float4*)ovp;
  float4 o1 = *(const float4*)(ovp + 4);
  float ov[8] = {o0.x, o0.y, o0.z, o0.w, o1.x, o1.y, o1.z, o1.w};
  float z = 0.f;
  #pragma unroll
  for (int t = 0; t < 2; ++t) {
    int kk = sub*2 + t;
    float x = HID[(size_t)r*128 + h*16 + kk] + pb1[h*16 + kk];
    float sg = 1.f / (1.f + expf(-x));
    z += x * sg * pw2[h*16 + kk];
  }
  z += __shfl_xor(z, 1); z += __shfl_xor(z, 2); z += __shfl_xor(z, 4);
  z += pb2[h];
  float p = 0.95f / (1.f + expf(-z));
  float nn = n2a[(size_t)r*8 + h] + n2b[(size_t)r*8 + h];
  float inv_n2 = 1.f / fmaxf(nn, 1e-24f);
  float base = (1.f - p) * 0.0078125f;   // (1-p)/128
  float rw[8];
  float rsum = 0.f;
  #pragma unroll
  for (int q = 0; q < 8; ++q) { rw[q] = p * (ov[q] * inv_n2) + base; rsum += rw[q]; }
  rsum += __shfl_xor(rsum, 1); rsum += __shfl_xor(rsum, 2); rsum += __shfl_xor(rsum, 4);
  float inv_den = 1.f / (rsum + 1e-8f);
  float a[8];
  #pragma unroll
  for (int q = 0; q < 8; ++q) a[q] = rw[q] * inv_den;
  float lg[8] = {0,0,0,0,0,0,0,0};
  const float* vgp = VG + (size_t)(h*64 + sub*8) * 8;
  #pragma unroll
  for (int q = 0; q < 8; ++q)
    #pragma unroll
    for (int g = 0; g < 8; ++g) lg[g] += a[q] * vgp[q*8 + g];
  #pragma unroll
  for (int off = 1; off < 64; off <<= 1)
    #pragma unroll
    for (int g = 0; g < 8; ++g) lg[g] += __shfl_xor(lg[g], off);
  float lt[8];
  #pragma unroll
  for (int g = 0; g < 8; ++g) lt[g] = lg[g] + gb[g];
  float mx = lt[0];
  #pragma unroll
  for (int g = 1; g < 8; ++g) mx = fmaxf(mx, lt[g]);
  float den = 0.f;
  #pragma unroll
  for (int g = 0; g < 8; ++g) den += expf(lt[g] - mx);
  float gate = expf(lt[h] - mx) / den;
  int mt = r >> 7, r8 = (r >> 4) & 7, r15 = r & 15;
  size_t basek = ((size_t)mt*16 + h*2 + (sub >> 2)) * 4096
               + (size_t)r8*512 + (size_t)(sub & 3)*128 + (size_t)r15*8;
  f16x8 hv, lv;
  #pragma unroll
  for (int q = 0; q < 8; ++q) {
    _Float16 hi, lo;
    split16(a[q] * gate, hi, lo);
    hv[q] = hi; lv[q] = lo;
  }
  *(f16x8*)(WH + basek) = hv;
  *(f16x8*)(WL + basek) = lv;
}

extern "C" void kernel_launch(void* const* d_in, const int* in_sizes, int n_in,
                              void* d_out, int out_size, void* d_ws, size_t ws_size,
                              hipStream_t stream) {
  const float* h_   = (const float*)d_in[0];
  const float* Wr   = (const float*)d_in[1];
  const float* Wi   = (const float*)d_in[2];
  const float* pw1  = (const float*)d_in[3];
  const float* pb1  = (const float*)d_in[4];
  const float* pw2  = (const float*)d_in[5];
  const float* pb2  = (const float*)d_in[6];
  const float* mr   = (const float*)d_in[7];
  const float* mi   = (const float*)d_in[8];
  const float* vals = (const float*)d_in[9];
  const float* gw   = (const float*)d_in[10];
  const float* gb   = (const float*)d_in[11];
  const float* ow   = (const float*)d_in[12];
  const float* ob   = (const float*)d_in[13];

  if (ws_size < WS_FLOATS * sizeof(float)) return;

  float* ws   = (float*)d_ws;
  float* OVL  = ws + OFF_OVL;
  float* HID  = ws + OFF_HID;
  float* n2a  = ws + OFF_N2;
  float* n2b  = ws + OFF_MRE;
  float* VG   = ws + OFF_VG;
  _Float16* VWH = (_Float16*)(ws + OFF_VWH);
  _Float16* VWL = (_Float16*)(ws + OFF_VWL);
  _Float16* BH  = (_Float16*)(ws + OFF_BH);
  _Float16* BL  = (_Float16*)(ws + OFF_BL);
  _Float16* AH  = (_Float16*)(ws + OFF_AH);
  _Float16* AL  = (_Float16*)(ws + OFF_AL);
  _Float16* WH  = (_Float16*)(ws + OFF_AH);  // alias: A dead after k_qval
  _Float16* WL  = (_Float16*)(ws + OFF_AL);

  k_prep_all<<<6080, 256, 0, stream>>>(h_, Wr, Wi, pw1, mr, mi, vals, gw, ow,
                                       VG, BH, BL, VWH, VWL, AH, AL);
  k_qnorm256<<<1024, 256, 0, stream>>>(AH, BH, n2a, n2b);
  k_qval<<<1152, 256, 0, stream>>>(AH, AL, BH, BL, OVL, HID);
  k_attn<<<4096, 256, 0, stream>>>(OVL, HID, n2a, n2b, VG, pb1, pw2, pb2, gb, WH, WL);
  k_fin<<<1024, 256, 0, stream>>>(WH, WL, VWH, VWL, ob, (float*)d_out);
}

// Round 19
// 369.384 us; speedup vs baseline: 1.1475x; 1.0318x over previous
//
#include <hip/hip_runtime.h>
#include <hip/hip_bf16.h>
#include <math.h>

#define ROWS 16384   // B*N = 8*2048

typedef _Float16 f16x8 __attribute__((ext_vector_type(8)));
typedef float f32x4 __attribute__((ext_vector_type(4)));

// ---- workspace offsets (floats); total identical to proven 31,330,304 ----
static const size_t OFF_OVL = 0;            // 16384*512 fp32 overlap
static const size_t OFF_HID = 8388608;      // 16384*128 fp32
static const size_t OFF_N2  = 10485760;     // 16384*8  (n2a)
static const size_t OFF_VG  = 10616832;     // 512*8
static const size_t OFF_MRE = 10620928;     // 65536 (n2b)
static const size_t OFF_MIM = 10686464;     // 65536 (unused)
static const size_t OFF_VWH = 10752000;     // 512*1024 f16 = 262144 fl
static const size_t OFF_VWL = 11014144;     // 262144 fl
static const size_t OFF_BH  = 11276288;     // 1024*3200 f16 = 1638400 fl
static const size_t OFF_BL  = 12914688;     // 1638400 fl
static const size_t OFF_AH  = 14553088;     // 16384*1024 f16 = 8388608 fl; late: WH alias
static const size_t OFF_AL  = 22941696;     // 8388608 fl; late: WL alias
static const size_t WS_FLOATS = 31330304;   // 125.32 MB

__device__ __forceinline__ void gload_lds16(const void* g, void* l) {
  __builtin_amdgcn_global_load_lds((const __attribute__((address_space(1))) void*)g,
                                   (__attribute__((address_space(3))) void*)l, 16, 0, 0);
}

__device__ __forceinline__ void split16(float v, _Float16& hi, _Float16& lo) {
  _Float16 h = (_Float16)v;
  hi = h;
  lo = (_Float16)(v - (float)h);
}

// ---------------- merged prep, long-first order: gemm64(0-127) | aov16(128-383) | vg(384-895) | b16(896-1983) | convA(1984-6079) ----------------
__global__ __launch_bounds__(256) void k_prep_all(const float* __restrict__ h_,
                                                  const float* __restrict__ Wr,
                                                  const float* __restrict__ Wi,
                                                  const float* __restrict__ pw1,
                                                  const float* __restrict__ mr,
                                                  const float* __restrict__ mi,
                                                  const float* __restrict__ vals,
                                                  const float* __restrict__ gw,
                                                  const float* __restrict__ ow,
                                                  float* __restrict__ VG,
                                                  _Float16* __restrict__ BH,
                                                  _Float16* __restrict__ BL,
                                                  _Float16* __restrict__ VWH,
                                                  _Float16* __restrict__ VWL,
                                                  _Float16* __restrict__ AH,
                                                  _Float16* __restrict__ AL) {
  __shared__ __align__(16) char pbuf[33024];
  const int b = blockIdx.x;
  const int tid = threadIdx.x;

  if (b < 128) {
    // ---- gemm64: VW = vals(512x1024) @ ow(1024x1024) -> VWH/VWL fragment tiles ----
    int sub = b;                        // 0..127
    int col0 = (sub & 15) << 6, row0 = (sub >> 4) << 6;
    float (*As)[64] = (float(*)[64])pbuf;
    float (*Bs)[64] = (float(*)[64])(pbuf + 4096);
    int tm = tid >> 4, tn = tid & 15;
    float acc[4][4];
    #pragma unroll
    for (int i = 0; i < 4; ++i)
      #pragma unroll
      for (int j = 0; j < 4; ++j) acc[i][j] = 0.f;
    int ar = tid >> 2, ak = (tid & 3) << 2;
    int bkr = tid >> 4, bc = (tid & 15) << 2;
    for (int kt = 0; kt < 1024; kt += 16) {
      float4 a0 = *(const float4*)(vals + (size_t)(row0 + ar)*1024 + kt + ak);
      float4 b0 = *(const float4*)(ow + (size_t)(kt + bkr)*1024 + col0 + bc);
      __syncthreads();
      As[ak+0][ar] = a0.x; As[ak+1][ar] = a0.y; As[ak+2][ar] = a0.z; As[ak+3][ar] = a0.w;
      *(float4*)&Bs[bkr][bc] = b0;
      __syncthreads();
      #pragma unroll
      for (int k = 0; k < 16; ++k) {
        float af[4], bf[4];
        *(float4*)&af[0] = *(const float4*)&As[k][tm << 2];
        *(float4*)&bf[0] = *(const float4*)&Bs[k][tn << 2];
        #pragma unroll
        for (int i = 0; i < 4; ++i)
          #pragma unroll
          for (int j = 0; j < 4; ++j) acc[i][j] += af[i] * bf[j];
      }
    }
    #pragma unroll
    for (int i = 0; i < 4; ++i) {
      int row = row0 + (tm << 2) + i;            // k-dim 0..511
      int ktl = row >> 5, kg = (row >> 3) & 3, jj = row & 7;
      #pragma unroll
      for (int j = 0; j < 4; ++j) {
        int col = col0 + (tn << 2) + j;          // 0..1023
        int nt = col >> 7, c8 = (col >> 4) & 7, c15 = col & 15;
        size_t base = ((size_t)nt*16 + ktl)*4096 + c8*512 + kg*128 + c15*8 + jj;
        _Float16 hi, lo; split16(acc[i][j], hi, lo);
        VWH[base] = hi; VWL[base] = lo;
      }
    }

  } else if (b < 384) {
    // ---- prep_aov16: normalize mr/mi in-LDS -> Aov -> BH/BL (nt 16..23) ----
    int bid = b - 128;             // h(8) x kt64(16) x shalf(2)
    int h   = bid >> 5;
    int kt64 = (bid >> 1) & 15;
    int sh  = bid & 1;
    float (*sRe)[129] = (float(*)[129])pbuf;
    float (*sIm)[129] = (float(*)[129])(pbuf + 16512);
    int s0 = sh * 32;
    for (int i = tid; i < 32 * 32; i += 256) {
      int s = i >> 5; int e4 = (i & 31) << 2;
      *(float4*)&sRe[s][e4] = *(const float4*)(mr + ((size_t)(h*64 + s0 + s)*128 + e4));
      *(float4*)&sIm[s][e4] = *(const float4*)(mi + ((size_t)(h*64 + s0 + s)*128 + e4));
    }
    __syncthreads();
    {
      int row = tid >> 3, part = tid & 7;
      float ss = 0.f;
      #pragma unroll
      for (int e = 0; e < 16; ++e) {
        float a = sRe[row][part*16 + e], bb = sIm[row][part*16 + e];
        ss += a*a + bb*bb;
      }
      ss += __shfl_xor(ss, 1); ss += __shfl_xor(ss, 2); ss += __shfl_xor(ss, 4);
      float inv = 1.f / fmaxf(sqrtf(ss), 1e-12f);
      #pragma unroll
      for (int e = 0; e < 16; ++e) {
        sRe[row][part*16 + e] *= inv;
        sIm[row][part*16 + e] *= inv;
      }
    }
    __syncthreads();
    int kq = tid >> 5;
    int s  = tid & 31;
    int kbase = kt64*64 + kq*8;
    float aR[8] = {0,0,0,0,0,0,0,0}, aI[8] = {0,0,0,0,0,0,0,0};
    for (int e0 = 0; e0 < 128; e0 += 4) {
      float4 mre = *(float4*)&sRe[s][e0];
      float4 mim = *(float4*)&sIm[s][e0];
      #pragma unroll
      for (int j = 0; j < 8; ++j) {
        const float4 wr = *(const float4*)(Wr + ((size_t)(h*1024 + kbase + j))*128 + e0);
        const float4 wi = *(const float4*)(Wi + ((size_t)(h*1024 + kbase + j))*128 + e0);
        aR[j] += wr.x*mre.x + wr.y*mre.y + wr.z*mre.z + wr.w*mre.w
               + wi.x*mim.x + wi.y*mim.y + wi.z*mim.z + wi.w*mim.w;
        aI[j] += wi.x*mre.x + wi.y*mre.y + wi.z*mre.z + wi.w*mre.w
               - (wr.x*mim.x + wr.y*mim.y + wr.z*mim.z + wr.w*mim.w);
      }
    }
    int kt32 = kbase >> 5;
    int kg   = (kbase >> 3) & 3;
    int coln = s0 + s;
    size_t baseR = ((size_t)(16 + h)*32 + kt32)*4096 + (size_t)(coln >> 4)*512 + kg*128 + (coln & 15)*8;
    size_t baseI = baseR + 4*512;
    f16x8 hR, lR, hI, lI;
    #pragma unroll
    for (int j = 0; j < 8; ++j) {
      _Float16 hi, lo;
      split16(aR[j], hi, lo); hR[j] = hi; lR[j] = lo;
      split16(aI[j], hi, lo); hI[j] = hi; lI[j] = lo;
    }
    *(f16x8*)(BH + baseR) = hR; *(f16x8*)(BL + baseR) = lR;
    *(f16x8*)(BH + baseI) = hI; *(f16x8*)(BL + baseI) = lI;

  } else if (b < 896) {
    // ---- prep_vg: VG[h,s,g] ----
    int hs = b - 384;
    int h  = hs >> 6;
    float acc[8] = {0,0,0,0,0,0,0,0};
    for (int dd = tid; dd < 1024; dd += 256) {
      float v = vals[(size_t)hs*1024 + dd];
      const float* g = gw + (size_t)(h*1024 + dd)*8;
      #pragma unroll
      for (int q = 0; q < 8; ++q) acc[q] += v * g[q];
    }
    #pragma unroll
    for (int off = 1; off < 64; off <<= 1)
      #pragma unroll
      for (int q = 0; q < 8; ++q) acc[q] += __shfl_xor(acc[q], off);
    float* red = (float*)pbuf;   // [4][8]
    if ((tid & 63) == 0) {
      #pragma unroll
      for (int q = 0; q < 8; ++q) red[(tid >> 6)*8 + q] = acc[q];
    }
    __syncthreads();
    if (tid < 8) VG[(size_t)hs*8 + tid] = red[tid] + red[8 + tid] + red[16 + tid] + red[24 + tid];

  } else if (b < 1984) {
    // ---- prep_b16: Wr/Wi/pw1 -> BH/BL fragment tiles ----
    int g = (b - 896) * 256 + tid;   // 128*2176 = 278528 total
    int c  = g % 2176;
    int k0 = g / 2176;
    float v[8];
    if (c < 1024) {
      int h = c >> 7, e = c & 127;
      const float* p = Wr + ((size_t)(h << 10) + k0*8) * 128 + e;
      #pragma unroll
      for (int j = 0; j < 8; ++j) v[j] = p[(size_t)j*128];
    } else if (c < 2048) {
      int c2 = c - 1024; int h = c2 >> 7, e = c2 & 127;
      const float* p = Wi + ((size_t)(h << 10) + k0*8) * 128 + e;
      #pragma unroll
      for (int j = 0; j < 8; ++j) v[j] = p[(size_t)j*128];
    } else {
      int q = c - 2048; int h = q >> 4, kk = q & 15;
      const float* p = pw1 + ((size_t)(h << 10) + k0*8) * 16 + kk;
      #pragma unroll
      for (int j = 0; j < 8; ++j) v[j] = p[(size_t)j*16];
    }
    int Bcol = (c < 2048) ? c : 3072 + (c - 2048);
    int nt = Bcol >> 7, c8 = (Bcol >> 4) & 7, c15 = Bcol & 15;
    int kt = k0 >> 2, kg = k0 & 3;
    size_t base = ((size_t)nt*32 + kt)*4096 + c8*512 + kg*128 + c15*8;
    f16x8 hv, lv;
    #pragma unroll
    for (int j = 0; j < 8; ++j) { _Float16 hi, lo; split16(v[j], hi, lo); hv[j] = hi; lv[j] = lo; }
    *(f16x8*)(BH + base) = hv;
    *(f16x8*)(BL + base) = lv;

  } else {
    // ---- convA: h row-major -> AH/AL fragment tiles ----
    int cb = b - 1984;                  // 0..4095
    int mt = cb >> 5, kt = cb & 31;
    size_t tbase = (size_t)cb * 4096;
    #pragma unroll
    for (int it = 0; it < 2; ++it) {
      int p = it*256 + tid;            // 0..511 = r8*64 + kg*16 + r15
      int r8 = p >> 6, kg = (p >> 4) & 3, r15 = p & 15;
      int row = mt*128 + r8*16 + r15;
      int col = kt*32 + kg*8;
      const float* s = h_ + (size_t)row*1024 + col;
      float4 v0 = *(const float4*)s;
      float4 v1 = *(const float4*)(s + 4);
      float vv[8] = {v0.x, v0.y, v0.z, v0.w, v1.x, v1.y, v1.z, v1.w};
      f16x8 hv, lv;
      #pragma unroll
      for (int j = 0; j < 8; ++j) { _Float16 hi, lo; split16(vv[j], hi, lo); hv[j] = hi; lv[j] = lo; }
      size_t i = tbase + (size_t)r8*512 + kg*128 + r15*8;
      *(f16x8*)(AH + i) = hv;
      *(f16x8*)(AL + i) = lv;
    }
  }
}

// ---------------- norm GEMM: hi-only, 128x256, counted-vmcnt pipeline; wave owns one head ----------------
__global__ __launch_bounds__(256) void k_qnorm256(const _Float16* __restrict__ Ah,
                                                  const _Float16* __restrict__ Bh,
                                                  float* __restrict__ n2a,
                                                  float* __restrict__ n2b) {
  __shared__ __align__(16) char smem[49152];   // 2 bufs x {A 8K, B0 8K, B1 8K}
  const int id = blockIdx.x;
  const int by = (id & 7) * 16 + ((id >> 3) & 15);
  const int bx = id >> 7;                      // 0..7
  const int tid = threadIdx.x;
  const int wid = tid >> 6, lane = tid & 63;
  const int wr = wid >> 1, wc = wid & 1;
  const char* gA  = (const char*)Ah + (size_t)by * 32 * 8192;
  const char* gB0 = (const char*)Bh + (size_t)(2*bx)     * 32 * 8192;
  const char* gB1 = (const char*)Bh + (size_t)(2*bx + 1) * 32 * 8192;

  f32x4 acc[4][8];
  #pragma unroll
  for (int i = 0; i < 4; ++i)
    #pragma unroll
    for (int j = 0; j < 8; ++j) acc[i][j] = (f32x4){0.f,0.f,0.f,0.f};

  auto stage = [&](int b, int kt) {
    char* dbuf = smem + b * 24576;
    #pragma unroll
    for (int q = 0; q < 6; ++q) {
      int c = wid * 6 + q;                     // 0..23 (wave-uniform)
      const char* s;
      if (c < 8)       s = gA  + (size_t)kt*8192 + c*1024;
      else if (c < 16) s = gB0 + (size_t)kt*8192 + (c-8)*1024;
      else             s = gB1 + (size_t)kt*8192 + (c-16)*1024;
      gload_lds16(s + lane*16, dbuf + c*1024);
    }
  };

  stage(0, 0);
  stage(1, 1);
  asm volatile("s_waitcnt vmcnt(6)" ::: "memory");
  __builtin_amdgcn_s_barrier();
  for (int kt = 0; kt < 32; ++kt) {
    const char* cb = smem + (kt & 1) * 24576;
    const char* bb = cb + 8192 + wc * 8192;
    f16x8 a[4], b[8];
    #pragma unroll
    for (int m = 0; m < 4; ++m) a[m] = *(const f16x8*)(cb + wr*4096 + m*1024 + lane*16);
    #pragma unroll
    for (int n = 0; n < 8; ++n) b[n] = *(const f16x8*)(bb + n*1024 + lane*16);
    asm volatile("s_waitcnt lgkmcnt(0)" ::: "memory");
    __builtin_amdgcn_s_barrier();
    if (kt < 30) stage(kt & 1, kt + 2);
    #pragma unroll
    for (int m = 0; m < 4; ++m)
      #pragma unroll
      for (int n = 0; n < 8; ++n)
        acc[m][n] = __builtin_amdgcn_mfma_f32_16x16x32_f16(a[m], b[n], acc[m][n], 0, 0, 0);
    if (kt < 31) {
      if (kt < 30) asm volatile("s_waitcnt vmcnt(6)" ::: "memory");
      else         asm volatile("s_waitcnt vmcnt(0)" ::: "memory");
      __builtin_amdgcn_s_barrier();
    }
  }

  const int nt = 2*bx + wc;
  float* dst = (nt < 8) ? n2a : n2b;
  const int head = nt & 7;
  #pragma unroll
  for (int m = 0; m < 4; ++m)
    #pragma unroll
    for (int rr = 0; rr < 4; ++rr) {
      float rs = 0.f;
      #pragma unroll
      for (int n = 0; n < 8; ++n) rs += acc[m][n][rr] * acc[m][n][rr];
      rs += __shfl_xor(rs, 1); rs += __shfl_xor(rs, 2);
      rs += __shfl_xor(rs, 4); rs += __shfl_xor(rs, 8);
      if ((lane & 15) == 0) {
        int row = by*128 + wr*64 + m*16 + (lane >> 4)*4 + rr;
        dst[(size_t)row*8 + head] = rs;
      }
    }
}

// ---------------- value GEMM: 3-term, 128x128, 2-barrier double-buffered (proven) ----------------
__global__ __launch_bounds__(256) void k_qval(const _Float16* __restrict__ Ah,
                                              const _Float16* __restrict__ Al,
                                              const _Float16* __restrict__ Bh,
                                              const _Float16* __restrict__ Bl,
                                              float* __restrict__ OVL,
                                              float* __restrict__ HID) {
  __shared__ __align__(16) char smem[65536];   // 2 bufs x {Ah,Al,Bh,Bl} x 8KB
  const int id = blockIdx.x;
  const int rest = id >> 3;
  const int by = (id & 7) * 16 + (rest & 15);
  const int bx = rest >> 4;                    // 0..8
  const int tid = threadIdx.x;
  const int wid = tid >> 6, lane = tid & 63;
  const int wr = wid >> 1, wc = wid & 1;
  f32x4 acc[4][4];
  #pragma unroll
  for (int i = 0; i < 4; ++i)
    #pragma unroll
    for (int j = 0; j < 4; ++j) acc[i][j] = (f32x4){0.f,0.f,0.f,0.f};

  const char* pAh = (const char*)Ah + (size_t)by*32*8192;
  const char* pAl = (const char*)Al + (size_t)by*32*8192;
  const char* pBh = (const char*)Bh + (size_t)(16 + bx)*32*8192;
  const char* pBl = (const char*)Bl + (size_t)(16 + bx)*32*8192;
  const char* mysrc = (wid == 0) ? pAh : (wid == 1) ? pAl : (wid == 2) ? pBh : pBl;

  auto stage = [&](int b, int kt) {
    const char* s = mysrc + (size_t)kt*8192 + lane*16;
    char* d = smem + b*32768 + wid*8192;
    #pragma unroll
    for (int q = 0; q < 8; ++q)
      gload_lds16(s + q*1024, d + q*1024);
  };

  stage(0, 0);
  asm volatile("s_waitcnt vmcnt(0)" ::: "memory");
  __builtin_amdgcn_s_barrier();
  int cur = 0;
  for (int kt = 0; kt < 32; ++kt) {
    if (kt < 31) stage(cur ^ 1, kt + 1);
    const char* base = smem + cur*32768;
    const char* cAh = base;
    const char* cAl = base + 8192;
    const char* cBh = base + 16384;
    const char* cBl = base + 24576;
    f16x8 a_h[4], a_l[4], b_h[4], b_l[4];
    #pragma unroll
    for (int m = 0; m < 4; ++m) { a_h[m] = *(const f16x8*)(cAh + wr*4096 + m*1024 + lane*16);
                                  a_l[m] = *(const f16x8*)(cAl + wr*4096 + m*1024 + lane*16); }
    #pragma unroll
    for (int n = 0; n < 4; ++n) { b_h[n] = *(const f16x8*)(cBh + wc*4096 + n*1024 + lane*16);
                                  b_l[n] = *(const f16x8*)(cBl + wc*4096 + n*1024 + lane*16); }
    #pragma unroll
    for (int m = 0; m < 4; ++m)
      #pragma unroll
      for (int n = 0; n < 4; ++n) {
        acc[m][n] = __builtin_amdgcn_mfma_f32_16x16x32_f16(a_h[m], b_h[n], acc[m][n], 0, 0, 0);
        acc[m][n] = __builtin_amdgcn_mfma_f32_16x16x32_f16(a_l[m], b_h[n], acc[m][n], 0, 0, 0);
        acc[m][n] = __builtin_amdgcn_mfma_f32_16x16x32_f16(a_h[m], b_l[n], acc[m][n], 0, 0, 0);
      }
    if (kt < 31) {
      asm volatile("s_waitcnt vmcnt(0)" ::: "memory");
      __builtin_amdgcn_s_barrier();
    }
    cur ^= 1;
  }
  __syncthreads();   // all waves done with LDS buffers before epilogue reuse

  if (bx == 8) {
    #pragma unroll
    for (int m = 0; m < 4; ++m)
      #pragma unroll
      for (int n = 0; n < 4; ++n)
        #pragma unroll
        for (int rr = 0; rr < 4; ++rr) {
          int row = by*128 + wr*64 + m*16 + (lane>>4)*4 + rr;
          int col = wc*64 + n*16 + (lane&15);
          HID[(size_t)row*128 + col] = acc[m][n][rr];
        }
  } else {
    float* sOv = (float*)smem;   // [128][68]
    if (wc == 0) {
      #pragma unroll
      for (int m = 0; m < 4; ++m)
        #pragma unroll
        for (int n = 0; n < 4; ++n)
          #pragma unroll
          for (int rr = 0; rr < 4; ++rr) {
            int r128 = wr*64 + m*16 + (lane>>4)*4 + rr;
            int s = n*16 + (lane&15);
            sOv[r128*68 + s] = acc[m][n][rr]*acc[m][n][rr];
          }
    }
    __syncthreads();
    if (wc == 1) {
      #pragma unroll
      for (int m = 0; m < 4; ++m)
        #pragma unroll
        for (int n = 0; n < 4; ++n)
          #pragma unroll
          for (int rr = 0; rr < 4; ++rr) {
            int r128 = wr*64 + m*16 + (lane>>4)*4 + rr;
            int s = n*16 + (lane&15);
            float v = sOv[r128*68 + s] + acc[m][n][rr]*acc[m][n][rr];
            int row = by*128 + r128;
            OVL[(size_t)row*512 + bx*64 + s] = v;
          }
    }
  }
}

// ---------------- final MFMA GEMM: counted-vmcnt pipeline; out = wattn @ VW + out_b ----------------
__global__ __launch_bounds__(256) void k_fin(const _Float16* __restrict__ Ahh,
                                             const _Float16* __restrict__ Alo,
                                             const _Float16* __restrict__ Bhh,
                                             const _Float16* __restrict__ Blo,
                                             const float* __restrict__ bias,
                                             float* __restrict__ out) {
  __shared__ __align__(16) char smem[65536];
  const int id = blockIdx.x;                   // 1024: XCD-partitioned decode
  const int by = (id & 7) * 16 + ((id >> 3) & 15);   // 0..127
  const int bx = id >> 7;                      // 0..7
  const int tid = threadIdx.x;
  const int wid = tid >> 6, lane = tid & 63;
  const int wr = wid >> 1, wc = wid & 1;
  f32x4 acc[4][4];
  #pragma unroll
  for (int i = 0; i < 4; ++i)
    #pragma unroll
    for (int j = 0; j < 4; ++j) acc[i][j] = (f32x4){0.f,0.f,0.f,0.f};
  const char* pAh = (const char*)Ahh + (size_t)by*16*8192;
  const char* pAl = (const char*)Alo + (size_t)by*16*8192;
  const char* pBh = (const char*)Bhh + (size_t)bx*16*8192;
  const char* pBl = (const char*)Blo + (size_t)bx*16*8192;
  const char* mysrc = (wid == 0) ? pAh : (wid == 1) ? pAl : (wid == 2) ? pBh : pBl;

  auto stage = [&](int b, int kt) {
    const char* s = mysrc + (size_t)kt*8192 + lane*16;
    char* d = smem + b*32768 + wid*8192;
    #pragma unroll
    for (int q = 0; q < 8; ++q)
      gload_lds16(s + q*1024, d + q*1024);
  };

  stage(0, 0);
  stage(1, 1);
  asm volatile("s_waitcnt vmcnt(8)" ::: "memory");
  __builtin_amdgcn_s_barrier();
  for (int kt = 0; kt < 16; ++kt) {
    const char* base = smem + (kt & 1)*32768;
    const char* cAh = base;
    const char* cAl = base + 8192;
    const char* cBh = base + 16384;
    const char* cBl = base + 24576;
    f16x8 a_h[4], a_l[4], b_h[4], b_l[4];
    #pragma unroll
    for (int m = 0; m < 4; ++m) { a_h[m] = *(const f16x8*)(cAh + wr*4096 + m*1024 + lane*16);
                                  a_l[m] = *(const f16x8*)(cAl + wr*4096 + m*1024 + lane*16); }
    #pragma unroll
    for (int n = 0; n < 4; ++n) { b_h[n] = *(const f16x8*)(cBh + wc*4096 + n*1024 + lane*16);
                                  b_l[n] = *(const f16x8*)(cBl + wc*4096 + n*1024 + lane*16); }
    asm volatile("s_waitcnt lgkmcnt(0)" ::: "memory");
    __builtin_amdgcn_s_barrier();
    if (kt < 14) stage(kt & 1, kt + 2);
    #pragma unroll
    for (int m = 0; m < 4; ++m)
      #pragma unroll
      for (int n = 0; n < 4; ++n) {
        acc[m][n] = __builtin_amdgcn_mfma_f32_16x16x32_f16(a_h[m], b_h[n], acc[m][n], 0, 0, 0);
        acc[m][n] = __builtin_amdgcn_mfma_f32_16x16x32_f16(a_l[m], b_h[n], acc[m][n], 0, 0, 0);
        acc[m][n] = __builtin_amdgcn_mfma_f32_16x16x32_f16(a_h[m], b_l[n], acc[m][n], 0, 0, 0);
      }
    if (kt < 15) {
      if (kt < 14) asm volatile("s_waitcnt vmcnt(8)" ::: "memory");
      else         asm volatile("s_waitcnt vmcnt(0)" ::: "memory");
      __builtin_amdgcn_s_barrier();
    }
  }
  #pragma unroll
  for (int m = 0; m < 4; ++m)
    #pragma unroll
    for (int n = 0; n < 4; ++n) {
      int col = bx*128 + wc*64 + n*16 + (lane&15);
      float bv = bias[col];
      #pragma unroll
      for (int rr = 0; rr < 4; ++rr) {
        int row = by*128 + wr*64 + m*16 + (lane>>4)*4 + rr;
        out[(size_t)row*1024 + col] = acc[m][n][rr] + bv;
      }
    }
}

// ---------------- per-row attention, wave-per-row (4 rows/block, no barriers/LDS) ----------------
__global__ __launch_bounds__(256) void k_attn(const float* __restrict__ OVL,
                                              const float* __restrict__ HID,
                                              const float* __restrict__ n2a,
                                              const float* __restrict__ n2b,
                                              const float* __restrict__ VG,
                                              const float* __restrict__ pb1,
                                              const float* __restrict__ pw2,
                                              const float* __restrict__ pb2,
                                              const float* __restrict__ gb,
                                              _Float16* __restrict__ WH,
                                              _Float16* __restrict__ WL) {
  const int wid = threadIdx.x >> 6;
  const int lane = threadIdx.x & 63;
  const int r = blockIdx.x * 4 + wid;          // one wave per row
  const int h = lane >> 3;                     // head 0..7 (8 lanes each)
  const int sub = lane & 7;                    // 8 s-values per lane
  const float* ovp = OVL + (size_t)r*512 + h*64 + sub*8;
  float4 o0 = *(const float4*)ovp;
  float4 o1 = *(const float4*)(ovp + 4);
  float ov[8] = {o0.x, o0.y, o0.z, o0.w, o1.x, o1.y, o1.z, o1.w};
  float z = 0.f;
  #pragma unroll
  for (int t = 0; t < 2; ++t) {
    int kk = sub*2 + t;
    float x = HID[(size_t)r*128 + h*16 + kk] + pb1[h*16 + kk];
    float sg = 1.f / (1.f + expf(-x));
    z += x * sg * pw2[h*16 + kk];
  }
  z += __shfl_xor(z, 1); z += __shfl_xor(z, 2); z += __shfl_xor(z, 4);
  z += pb2[h];
  float p = 0.95f / (1.f + expf(-z));
  float nn = n2a[(size_t)r*8 + h] + n2b[(size_t)r*8 + h];
  float inv_n2 = 1.f / fmaxf(nn, 1e-24f);
  float base = (1.f - p) * 0.0078125f;   // (1-p)/128
  float rw[8];
  float rsum = 0.f;
  #pragma unroll
  for (int q = 0; q < 8; ++q) { rw[q] = p * (ov[q] * inv_n2) + base; rsum += rw[q]; }
  rsum += __shfl_xor(rsum, 1); rsum += __shfl_xor(rsum, 2); rsum += __shfl_xor(rsum, 4);
  float inv_den = 1.f / (rsum + 1e-8f);
  float a[8];
  #pragma unroll
  for (int q = 0; q < 8; ++q) a[q] = rw[q] * inv_den;
  float lg[8] = {0,0,0,0,0,0,0,0};
  const float* vgp = VG + (size_t)(h*64 + sub*8) * 8;
  #pragma unroll
  for (int q = 0; q < 8; ++q)
    #pragma unroll
    for (int g = 0; g < 8; ++g) lg[g] += a[q] * vgp[q*8 + g];
  #pragma unroll
  for (int off = 1; off < 64; off <<= 1)
    #pragma unroll
    for (int g = 0; g < 8; ++g) lg[g] += __shfl_xor(lg[g], off);
  float lt[8];
  #pragma unroll
  for (int g = 0; g < 8; ++g) lt[g] = lg[g] + gb[g];
  float mx = lt[0];
  #pragma unroll
  for (int g = 1; g < 8; ++g) mx = fmaxf(mx, lt[g]);
  float den = 0.f;
  #pragma unroll
  for (int g = 0; g < 8; ++g) den += expf(lt[g] - mx);
  float gate = expf(lt[h] - mx) / den;
  int mt = r >> 7, r8 = (r >> 4) & 7, r15 = r & 15;
  size_t basek = ((size_t)mt*16 + h*2 + (sub >> 2)) * 4096
               + (size_t)r8*512 + (size_t)(sub & 3)*128 + (size_t)r15*8;
  f16x8 hv, lv;
  #pragma unroll
  for (int q = 0; q < 8; ++q) {
    _Float16 hi, lo;
    split16(a[q] * gate, hi, lo);
    hv[q] = hi; lv[q] = lo;
  }
  *(f16x8*)(WH + basek) = hv;
  *(f16x8*)(WL + basek) = lv;
}

extern "C" void kernel_launch(void* const* d_in, const int* in_sizes, int n_in,
                              void* d_out, int out_size, void* d_ws, size_t ws_size,
                              hipStream_t stream) {
  const float* h_   = (const float*)d_in[0];
  const float* Wr   = (const float*)d_in[1];
  const float* Wi   = (const float*)d_in[2];
  const float* pw1  = (const float*)d_in[3];
  const float* pb1  = (const float*)d_in[4];
  const float* pw2  = (const float*)d_in[5];
  const float* pb2  = (const float*)d_in[6];
  const float* mr   = (const float*)d_in[7];
  const float* mi   = (const float*)d_in[8];
  const float* vals = (const float*)d_in[9];
  const float* gw   = (const float*)d_in[10];
  const float* gb   = (const float*)d_in[11];
  const float* ow   = (const float*)d_in[12];
  const float* ob   = (const float*)d_in[13];

  if (ws_size < WS_FLOATS * sizeof(float)) return;

  float* ws   = (float*)d_ws;
  float* OVL  = ws + OFF_OVL;
  float* HID  = ws + OFF_HID;
  float* n2a  = ws + OFF_N2;
  float* n2b  = ws + OFF_MRE;
  float* VG   = ws + OFF_VG;
  _Float16* VWH = (_Float16*)(ws + OFF_VWH);
  _Float16* VWL = (_Float16*)(ws + OFF_VWL);
  _Float16* BH  = (_Float16*)(ws + OFF_BH);
  _Float16* BL  = (_Float16*)(ws + OFF_BL);
  _Float16* AH  = (_Float16*)(ws + OFF_AH);
  _Float16* AL  = (_Float16*)(ws + OFF_AL);
  _Float16* WH  = (_Float16*)(ws + OFF_AH);  // alias: A dead after k_qval
  _Float16* WL  = (_Float16*)(ws + OFF_AL);

  k_prep_all<<<6080, 256, 0, stream>>>(h_, Wr, Wi, pw1, mr, mi, vals, gw, ow,
                                       VG, BH, BL, VWH, VWL, AH, AL);
  k_qnorm256<<<1024, 256, 0, stream>>>(AH, BH, n2a, n2b);
  k_qval<<<1152, 256, 0, stream>>>(AH, AL, BH, BL, OVL, HID);
  k_attn<<<4096, 256, 0, stream>>>(OVL, HID, n2a, n2b, VG, pb1, pw2, pb2, gb, WH, WL);
  k_fin<<<1024, 256, 0, stream>>>(WH, WL, VWH, VWL, ob, (float*)d_out);
}

// Round 20
// 357.712 us; speedup vs baseline: 1.1849x; 1.0326x over previous
//
#include <hip/hip_runtime.h>
#include <hip/hip_bf16.h>
#include <math.h>

#define ROWS 16384   // B*N = 8*2048

typedef _Float16 f16x8 __attribute__((ext_vector_type(8)));
typedef float f32x4 __attribute__((ext_vector_type(4)));

// ---- workspace offsets (floats); total identical to proven 31,330,304 ----
static const size_t OFF_OVL = 0;            // 16384*512 fp32 overlap
static const size_t OFF_HID = 8388608;      // 16384*128 fp32
static const size_t OFF_N2  = 10485760;     // 16384*8  (n2a)
static const size_t OFF_VG  = 10616832;     // 512*8
static const size_t OFF_MRE = 10620928;     // 65536 (n2b)
static const size_t OFF_MIM = 10686464;     // 65536 (unused)
static const size_t OFF_VWH = 10752000;     // 512*1024 f16 = 262144 fl
static const size_t OFF_VWL = 11014144;     // 262144 fl
static const size_t OFF_BH  = 11276288;     // 1024*3200 f16 = 1638400 fl
static const size_t OFF_BL  = 12914688;     // 1638400 fl
static const size_t OFF_AH  = 14553088;     // 16384*1024 f16 = 8388608 fl; late: WH alias
static const size_t OFF_AL  = 22941696;     // 8388608 fl; late: WL alias
static const size_t WS_FLOATS = 31330304;   // 125.32 MB

__device__ __forceinline__ void gload_lds16(const void* g, void* l) {
  __builtin_amdgcn_global_load_lds((const __attribute__((address_space(1))) void*)g,
                                   (__attribute__((address_space(3))) void*)l, 16, 0, 0);
}

__device__ __forceinline__ void split16(float v, _Float16& hi, _Float16& lo) {
  _Float16 h = (_Float16)v;
  hi = h;
  lo = (_Float16)(v - (float)h);
}

// ---------------- merged prep, long-first order: gemm64(0-127) | aov16(128-383) | vg(384-895) | b16(896-1983) | convA(1984-6079) ----------------
__global__ __launch_bounds__(256) void k_prep_all(const float* __restrict__ h_,
                                                  const float* __restrict__ Wr,
                                                  const float* __restrict__ Wi,
                                                  const float* __restrict__ pw1,
                                                  const float* __restrict__ mr,
                                                  const float* __restrict__ mi,
                                                  const float* __restrict__ vals,
                                                  const float* __restrict__ gw,
                                                  const float* __restrict__ ow,
                                                  float* __restrict__ VG,
                                                  _Float16* __restrict__ BH,
                                                  _Float16* __restrict__ BL,
                                                  _Float16* __restrict__ VWH,
                                                  _Float16* __restrict__ VWL,
                                                  _Float16* __restrict__ AH,
                                                  _Float16* __restrict__ AL) {
  __shared__ __align__(16) char pbuf[33024];
  const int b = blockIdx.x;
  const int tid = threadIdx.x;

  if (b < 128) {
    // ---- gemm64: VW = vals(512x1024) @ ow(1024x1024) -> VWH/VWL fragment tiles ----
    int sub = b;                        // 0..127
    int col0 = (sub & 15) << 6, row0 = (sub >> 4) << 6;
    float (*As)[64] = (float(*)[64])pbuf;
    float (*Bs)[64] = (float(*)[64])(pbuf + 4096);
    int tm = tid >> 4, tn = tid & 15;
    float acc[4][4];
    #pragma unroll
    for (int i = 0; i < 4; ++i)
      #pragma unroll
      for (int j = 0; j < 4; ++j) acc[i][j] = 0.f;
    int ar = tid >> 2, ak = (tid & 3) << 2;
    int bkr = tid >> 4, bc = (tid & 15) << 2;
    for (int kt = 0; kt < 1024; kt += 16) {
      float4 a0 = *(const float4*)(vals + (size_t)(row0 + ar)*1024 + kt + ak);
      float4 b0 = *(const float4*)(ow + (size_t)(kt + bkr)*1024 + col0 + bc);
      __syncthreads();
      As[ak+0][ar] = a0.x; As[ak+1][ar] = a0.y; As[ak+2][ar] = a0.z; As[ak+3][ar] = a0.w;
      *(float4*)&Bs[bkr][bc] = b0;
      __syncthreads();
      #pragma unroll
      for (int k = 0; k < 16; ++k) {
        float af[4], bf[4];
        *(float4*)&af[0] = *(const float4*)&As[k][tm << 2];
        *(float4*)&bf[0] = *(const float4*)&Bs[k][tn << 2];
        #pragma unroll
        for (int i = 0; i < 4; ++i)
          #pragma unroll
          for (int j = 0; j < 4; ++j) acc[i][j] += af[i] * bf[j];
      }
    }
    #pragma unroll
    for (int i = 0; i < 4; ++i) {
      int row = row0 + (tm << 2) + i;            // k-dim 0..511
      int ktl = row >> 5, kg = (row >> 3) & 3, jj = row & 7;
      #pragma unroll
      for (int j = 0; j < 4; ++j) {
        int col = col0 + (tn << 2) + j;          // 0..1023
        int nt = col >> 7, c8 = (col >> 4) & 7, c15 = col & 15;
        size_t base = ((size_t)nt*16 + ktl)*4096 + c8*512 + kg*128 + c15*8 + jj;
        _Float16 hi, lo; split16(acc[i][j], hi, lo);
        VWH[base] = hi; VWL[base] = lo;
      }
    }

  } else if (b < 384) {
    // ---- prep_aov16: normalize mr/mi in-LDS -> Aov -> BH/BL (nt 16..23) ----
    int bid = b - 128;             // h(8) x kt64(16) x shalf(2)
    int h   = bid >> 5;
    int kt64 = (bid >> 1) & 15;
    int sh  = bid & 1;
    float (*sRe)[129] = (float(*)[129])pbuf;
    float (*sIm)[129] = (float(*)[129])(pbuf + 16512);
    int s0 = sh * 32;
    for (int i = tid; i < 32 * 32; i += 256) {
      int s = i >> 5; int e4 = (i & 31) << 2;
      *(float4*)&sRe[s][e4] = *(const float4*)(mr + ((size_t)(h*64 + s0 + s)*128 + e4));
      *(float4*)&sIm[s][e4] = *(const float4*)(mi + ((size_t)(h*64 + s0 + s)*128 + e4));
    }
    __syncthreads();
    {
      int row = tid >> 3, part = tid & 7;
      float ss = 0.f;
      #pragma unroll
      for (int e = 0; e < 16; ++e) {
        float a = sRe[row][part*16 + e], bb = sIm[row][part*16 + e];
        ss += a*a + bb*bb;
      }
      ss += __shfl_xor(ss, 1); ss += __shfl_xor(ss, 2); ss += __shfl_xor(ss, 4);
      float inv = 1.f / fmaxf(sqrtf(ss), 1e-12f);
      #pragma unroll
      for (int e = 0; e < 16; ++e) {
        sRe[row][part*16 + e] *= inv;
        sIm[row][part*16 + e] *= inv;
      }
    }
    __syncthreads();
    int kq = tid >> 5;
    int s  = tid & 31;
    int kbase = kt64*64 + kq*8;
    float aR[8] = {0,0,0,0,0,0,0,0}, aI[8] = {0,0,0,0,0,0,0,0};
    for (int e0 = 0; e0 < 128; e0 += 4) {
      float4 mre = *(float4*)&sRe[s][e0];
      float4 mim = *(float4*)&sIm[s][e0];
      #pragma unroll
      for (int j = 0; j < 8; ++j) {
        const float4 wr = *(const float4*)(Wr + ((size_t)(h*1024 + kbase + j))*128 + e0);
        const float4 wi = *(const float4*)(Wi + ((size_t)(h*1024 + kbase + j))*128 + e0);
        aR[j] += wr.x*mre.x + wr.y*mre.y + wr.z*mre.z + wr.w*mre.w
               + wi.x*mim.x + wi.y*mim.y + wi.z*mim.z + wi.w*mim.w;
        aI[j] += wi.x*mre.x + wi.y*mre.y + wi.z*mre.z + wi.w*mre.w
               - (wr.x*mim.x + wr.y*mim.y + wr.z*mim.z + wr.w*mim.w);
      }
    }
    int kt32 = kbase >> 5;
    int kg   = (kbase >> 3) & 3;
    int coln = s0 + s;
    size_t baseR = ((size_t)(16 + h)*32 + kt32)*4096 + (size_t)(coln >> 4)*512 + kg*128 + (coln & 15)*8;
    size_t baseI = baseR + 4*512;
    f16x8 hR, lR, hI, lI;
    #pragma unroll
    for (int j = 0; j < 8; ++j) {
      _Float16 hi, lo;
      split16(aR[j], hi, lo); hR[j] = hi; lR[j] = lo;
      split16(aI[j], hi, lo); hI[j] = hi; lI[j] = lo;
    }
    *(f16x8*)(BH + baseR) = hR; *(f16x8*)(BL + baseR) = lR;
    *(f16x8*)(BH + baseI) = hI; *(f16x8*)(BL + baseI) = lI;

  } else if (b < 896) {
    // ---- prep_vg: VG[h,s,g] ----
    int hs = b - 384;
    int h  = hs >> 6;
    float acc[8] = {0,0,0,0,0,0,0,0};
    for (int dd = tid; dd < 1024; dd += 256) {
      float v = vals[(size_t)hs*1024 + dd];
      const float* g = gw + (size_t)(h*1024 + dd)*8;
      #pragma unroll
      for (int q = 0; q < 8; ++q) acc[q] += v * g[q];
    }
    #pragma unroll
    for (int off = 1; off < 64; off <<= 1)
      #pragma unroll
      for (int q = 0; q < 8; ++q) acc[q] += __shfl_xor(acc[q], off);
    float* red = (float*)pbuf;   // [4][8]
    if ((tid & 63) == 0) {
      #pragma unroll
      for (int q = 0; q < 8; ++q) red[(tid >> 6)*8 + q] = acc[q];
    }
    __syncthreads();
    if (tid < 8) VG[(size_t)hs*8 + tid] = red[tid] + red[8 + tid] + red[16 + tid] + red[24 + tid];

  } else if (b < 1984) {
    // ---- prep_b16: Wr/Wi/pw1 -> BH/BL fragment tiles ----
    int g = (b - 896) * 256 + tid;   // 128*2176 = 278528 total
    int c  = g % 2176;
    int k0 = g / 2176;
    float v[8];
    if (c < 1024) {
      int h = c >> 7, e = c & 127;
      const float* p = Wr + ((size_t)(h << 10) + k0*8) * 128 + e;
      #pragma unroll
      for (int j = 0; j < 8; ++j) v[j] = p[(size_t)j*128];
    } else if (c < 2048) {
      int c2 = c - 1024; int h = c2 >> 7, e = c2 & 127;
      const float* p = Wi + ((size_t)(h << 10) + k0*8) * 128 + e;
      #pragma unroll
      for (int j = 0; j < 8; ++j) v[j] = p[(size_t)j*128];
    } else {
      int q = c - 2048; int h = q >> 4, kk = q & 15;
      const float* p = pw1 + ((size_t)(h << 10) + k0*8) * 16 + kk;
      #pragma unroll
      for (int j = 0; j < 8; ++j) v[j] = p[(size_t)j*16];
    }
    int Bcol = (c < 2048) ? c : 3072 + (c - 2048);
    int nt = Bcol >> 7, c8 = (Bcol >> 4) & 7, c15 = Bcol & 15;
    int kt = k0 >> 2, kg = k0 & 3;
    size_t base = ((size_t)nt*32 + kt)*4096 + c8*512 + kg*128 + c15*8;
    f16x8 hv, lv;
    #pragma unroll
    for (int j = 0; j < 8; ++j) { _Float16 hi, lo; split16(v[j], hi, lo); hv[j] = hi; lv[j] = lo; }
    *(f16x8*)(BH + base) = hv;
    *(f16x8*)(BL + base) = lv;

  } else {
    // ---- convA: h row-major -> AH/AL fragment tiles ----
    int cb = b - 1984;                  // 0..4095
    int mt = cb >> 5, kt = cb & 31;
    size_t tbase = (size_t)cb * 4096;
    #pragma unroll
    for (int it = 0; it < 2; ++it) {
      int p = it*256 + tid;            // 0..511 = r8*64 + kg*16 + r15
      int r8 = p >> 6, kg = (p >> 4) & 3, r15 = p & 15;
      int row = mt*128 + r8*16 + r15;
      int col = kt*32 + kg*8;
      const float* s = h_ + (size_t)row*1024 + col;
      float4 v0 = *(const float4*)s;
      float4 v1 = *(const float4*)(s + 4);
      float vv[8] = {v0.x, v0.y, v0.z, v0.w, v1.x, v1.y, v1.z, v1.w};
      f16x8 hv, lv;
      #pragma unroll
      for (int j = 0; j < 8; ++j) { _Float16 hi, lo; split16(vv[j], hi, lo); hv[j] = hi; lv[j] = lo; }
      size_t i = tbase + (size_t)r8*512 + kg*128 + r15*8;
      *(f16x8*)(AH + i) = hv;
      *(f16x8*)(AL + i) = lv;
    }
  }
}

// ---------------- merged MFMA GEMM: qval (0..1151) | qnorm256 (1152..2175), one tile per block ----------------
__global__ __launch_bounds__(256) void k_qmm(const _Float16* __restrict__ Ah,
                                             const _Float16* __restrict__ Al,
                                             const _Float16* __restrict__ Bh,
                                             const _Float16* __restrict__ Bl,
                                             float* __restrict__ OVL,
                                             float* __restrict__ HID,
                                             float* __restrict__ n2a,
                                             float* __restrict__ n2b) {
  __shared__ __align__(16) char smem[65536];
  const int gid = blockIdx.x;
  const int tid = threadIdx.x;
  const int wid = tid >> 6, lane = tid & 63;
  const int wr = wid >> 1, wc = wid & 1;

  if (gid < 1152) {
    // ======== qval: 3-term, 128x128, 2-barrier double-buffered (proven) ========
    const int id = gid;
    const int rest = id >> 3;
    const int by = (id & 7) * 16 + (rest & 15);
    const int bx = rest >> 4;                    // 0..8
    f32x4 acc[4][4];
    #pragma unroll
    for (int i = 0; i < 4; ++i)
      #pragma unroll
      for (int j = 0; j < 4; ++j) acc[i][j] = (f32x4){0.f,0.f,0.f,0.f};

    const char* pAh = (const char*)Ah + (size_t)by*32*8192;
    const char* pAl = (const char*)Al + (size_t)by*32*8192;
    const char* pBh = (const char*)Bh + (size_t)(16 + bx)*32*8192;
    const char* pBl = (const char*)Bl + (size_t)(16 + bx)*32*8192;
    const char* mysrc = (wid == 0) ? pAh : (wid == 1) ? pAl : (wid == 2) ? pBh : pBl;

    auto stage = [&](int b, int kt) {
      const char* s = mysrc + (size_t)kt*8192 + lane*16;
      char* d = smem + b*32768 + wid*8192;
      #pragma unroll
      for (int q = 0; q < 8; ++q)
        gload_lds16(s + q*1024, d + q*1024);
    };

    stage(0, 0);
    asm volatile("s_waitcnt vmcnt(0)" ::: "memory");
    __builtin_amdgcn_s_barrier();
    int cur = 0;
    for (int kt = 0; kt < 32; ++kt) {
      if (kt < 31) stage(cur ^ 1, kt + 1);
      const char* base = smem + cur*32768;
      const char* cAh = base;
      const char* cAl = base + 8192;
      const char* cBh = base + 16384;
      const char* cBl = base + 24576;
      f16x8 a_h[4], a_l[4], b_h[4], b_l[4];
      #pragma unroll
      for (int m = 0; m < 4; ++m) { a_h[m] = *(const f16x8*)(cAh + wr*4096 + m*1024 + lane*16);
                                    a_l[m] = *(const f16x8*)(cAl + wr*4096 + m*1024 + lane*16); }
      #pragma unroll
      for (int n = 0; n < 4; ++n) { b_h[n] = *(const f16x8*)(cBh + wc*4096 + n*1024 + lane*16);
                                    b_l[n] = *(const f16x8*)(cBl + wc*4096 + n*1024 + lane*16); }
      #pragma unroll
      for (int m = 0; m < 4; ++m)
        #pragma unroll
        for (int n = 0; n < 4; ++n) {
          acc[m][n] = __builtin_amdgcn_mfma_f32_16x16x32_f16(a_h[m], b_h[n], acc[m][n], 0, 0, 0);
          acc[m][n] = __builtin_amdgcn_mfma_f32_16x16x32_f16(a_l[m], b_h[n], acc[m][n], 0, 0, 0);
          acc[m][n] = __builtin_amdgcn_mfma_f32_16x16x32_f16(a_h[m], b_l[n], acc[m][n], 0, 0, 0);
        }
      if (kt < 31) {
        asm volatile("s_waitcnt vmcnt(0)" ::: "memory");
        __builtin_amdgcn_s_barrier();
      }
      cur ^= 1;
    }
    __syncthreads();   // all waves done with LDS buffers before epilogue reuse

    if (bx == 8) {
      #pragma unroll
      for (int m = 0; m < 4; ++m)
        #pragma unroll
        for (int n = 0; n < 4; ++n)
          #pragma unroll
          for (int rr = 0; rr < 4; ++rr) {
            int row = by*128 + wr*64 + m*16 + (lane>>4)*4 + rr;
            int col = wc*64 + n*16 + (lane&15);
            HID[(size_t)row*128 + col] = acc[m][n][rr];
          }
    } else {
      float* sOv = (float*)smem;   // [128][68]
      if (wc == 0) {
        #pragma unroll
        for (int m = 0; m < 4; ++m)
          #pragma unroll
          for (int n = 0; n < 4; ++n)
            #pragma unroll
            for (int rr = 0; rr < 4; ++rr) {
              int r128 = wr*64 + m*16 + (lane>>4)*4 + rr;
              int s = n*16 + (lane&15);
              sOv[r128*68 + s] = acc[m][n][rr]*acc[m][n][rr];
            }
      }
      __syncthreads();
      if (wc == 1) {
        #pragma unroll
        for (int m = 0; m < 4; ++m)
          #pragma unroll
          for (int n = 0; n < 4; ++n)
            #pragma unroll
            for (int rr = 0; rr < 4; ++rr) {
              int r128 = wr*64 + m*16 + (lane>>4)*4 + rr;
              int s = n*16 + (lane&15);
              float v = sOv[r128*68 + s] + acc[m][n][rr]*acc[m][n][rr];
              int row = by*128 + r128;
              OVL[(size_t)row*512 + bx*64 + s] = v;
            }
      }
    }

  } else {
    // ======== qnorm256: hi-only, 128x256, counted-vmcnt pipeline; wave owns one head ========
    const int id = gid - 1152;
    const int by = (id & 7) * 16 + ((id >> 3) & 15);
    const int bx = id >> 7;                      // 0..7
    const char* gA  = (const char*)Ah + (size_t)by * 32 * 8192;
    const char* gB0 = (const char*)Bh + (size_t)(2*bx)     * 32 * 8192;
    const char* gB1 = (const char*)Bh + (size_t)(2*bx + 1) * 32 * 8192;

    f32x4 acc[4][8];
    #pragma unroll
    for (int i = 0; i < 4; ++i)
      #pragma unroll
      for (int j = 0; j < 8; ++j) acc[i][j] = (f32x4){0.f,0.f,0.f,0.f};

    auto stage = [&](int b, int kt) {
      char* dbuf = smem + b * 24576;
      #pragma unroll
      for (int q = 0; q < 6; ++q) {
        int c = wid * 6 + q;                     // 0..23 (wave-uniform)
        const char* s;
        if (c < 8)       s = gA  + (size_t)kt*8192 + c*1024;
        else if (c < 16) s = gB0 + (size_t)kt*8192 + (c-8)*1024;
        else             s = gB1 + (size_t)kt*8192 + (c-16)*1024;
        gload_lds16(s + lane*16, dbuf + c*1024);
      }
    };

    stage(0, 0);
    stage(1, 1);
    asm volatile("s_waitcnt vmcnt(6)" ::: "memory");
    __builtin_amdgcn_s_barrier();
    for (int kt = 0; kt < 32; ++kt) {
      const char* cb = smem + (kt & 1) * 24576;
      const char* bb = cb + 8192 + wc * 8192;
      f16x8 a[4], b[8];
      #pragma unroll
      for (int m = 0; m < 4; ++m) a[m] = *(const f16x8*)(cb + wr*4096 + m*1024 + lane*16);
      #pragma unroll
      for (int n = 0; n < 8; ++n) b[n] = *(const f16x8*)(bb + n*1024 + lane*16);
      asm volatile("s_waitcnt lgkmcnt(0)" ::: "memory");
      __builtin_amdgcn_s_barrier();
      if (kt < 30) stage(kt & 1, kt + 2);
      #pragma unroll
      for (int m = 0; m < 4; ++m)
        #pragma unroll
        for (int n = 0; n < 8; ++n)
          acc[m][n] = __builtin_amdgcn_mfma_f32_16x16x32_f16(a[m], b[n], acc[m][n], 0, 0, 0);
      if (kt < 31) {
        if (kt < 30) asm volatile("s_waitcnt vmcnt(6)" ::: "memory");
        else         asm volatile("s_waitcnt vmcnt(0)" ::: "memory");
        __builtin_amdgcn_s_barrier();
      }
    }

    const int nt = 2*bx + wc;
    float* dst = (nt < 8) ? n2a : n2b;
    const int head = nt & 7;
    #pragma unroll
    for (int m = 0; m < 4; ++m)
      #pragma unroll
      for (int rr = 0; rr < 4; ++rr) {
        float rs = 0.f;
        #pragma unroll
        for (int n = 0; n < 8; ++n) rs += acc[m][n][rr] * acc[m][n][rr];
        rs += __shfl_xor(rs, 1); rs += __shfl_xor(rs, 2);
        rs += __shfl_xor(rs, 4); rs += __shfl_xor(rs, 8);
        if ((lane & 15) == 0) {
          int row = by*128 + wr*64 + m*16 + (lane >> 4)*4 + rr;
          dst[(size_t)row*8 + head] = rs;
        }
      }
  }
}

// ---------------- final MFMA GEMM: counted-vmcnt pipeline; out = wattn @ VW + out_b ----------------
__global__ __launch_bounds__(256) void k_fin(const _Float16* __restrict__ Ahh,
                                             const _Float16* __restrict__ Alo,
                                             const _Float16* __restrict__ Bhh,
                                             const _Float16* __restrict__ Blo,
                                             const float* __restrict__ bias,
                                             float* __restrict__ out) {
  __shared__ __align__(16) char smem[65536];
  const int id = blockIdx.x;                   // 1024: XCD-partitioned decode
  const int by = (id & 7) * 16 + ((id >> 3) & 15);   // 0..127
  const int bx = id >> 7;                      // 0..7
  const int tid = threadIdx.x;
  const int wid = tid >> 6, lane = tid & 63;
  const int wr = wid >> 1, wc = wid & 1;
  f32x4 acc[4][4];
  #pragma unroll
  for (int i = 0; i < 4; ++i)
    #pragma unroll
    for (int j = 0; j < 4; ++j) acc[i][j] = (f32x4){0.f,0.f,0.f,0.f};
  const char* pAh = (const char*)Ahh + (size_t)by*16*8192;
  const char* pAl = (const char*)Alo + (size_t)by*16*8192;
  const char* pBh = (const char*)Bhh + (size_t)bx*16*8192;
  const char* pBl = (const char*)Blo + (size_t)bx*16*8192;
  const char* mysrc = (wid == 0) ? pAh : (wid == 1) ? pAl : (wid == 2) ? pBh : pBl;

  auto stage = [&](int b, int kt) {
    const char* s = mysrc + (size_t)kt*8192 + lane*16;
    char* d = smem + b*32768 + wid*8192;
    #pragma unroll
    for (int q = 0; q < 8; ++q)
      gload_lds16(s + q*1024, d + q*1024);
  };

  stage(0, 0);
  stage(1, 1);
  asm volatile("s_waitcnt vmcnt(8)" ::: "memory");
  __builtin_amdgcn_s_barrier();
  for (int kt = 0; kt < 16; ++kt) {
    const char* base = smem + (kt & 1)*32768;
    const char* cAh = base;
    const char* cAl = base + 8192;
    const char* cBh = base + 16384;
    const char* cBl = base + 24576;
    f16x8 a_h[4], a_l[4], b_h[4], b_l[4];
    #pragma unroll
    for (int m = 0; m < 4; ++m) { a_h[m] = *(const f16x8*)(cAh + wr*4096 + m*1024 + lane*16);
                                  a_l[m] = *(const f16x8*)(cAl + wr*4096 + m*1024 + lane*16); }
    #pragma unroll
    for (int n = 0; n < 4; ++n) { b_h[n] = *(const f16x8*)(cBh + wc*4096 + n*1024 + lane*16);
                                  b_l[n] = *(const f16x8*)(cBl + wc*4096 + n*1024 + lane*16); }
    asm volatile("s_waitcnt lgkmcnt(0)" ::: "memory");
    __builtin_amdgcn_s_barrier();
    if (kt < 14) stage(kt & 1, kt + 2);
    #pragma unroll
    for (int m = 0; m < 4; ++m)
      #pragma unroll
      for (int n = 0; n < 4; ++n) {
        acc[m][n] = __builtin_amdgcn_mfma_f32_16x16x32_f16(a_h[m], b_h[n], acc[m][n], 0, 0, 0);
        acc[m][n] = __builtin_amdgcn_mfma_f32_16x16x32_f16(a_l[m], b_h[n], acc[m][n], 0, 0, 0);
        acc[m][n] = __builtin_amdgcn_mfma_f32_16x16x32_f16(a_h[m], b_l[n], acc[m][n], 0, 0, 0);
      }
    if (kt < 15) {
      if (kt < 14) asm volatile("s_waitcnt vmcnt(8)" ::: "memory");
      else         asm volatile("s_waitcnt vmcnt(0)" ::: "memory");
      __builtin_amdgcn_s_barrier();
    }
  }
  #pragma unroll
  for (int m = 0; m < 4; ++m)
    #pragma unroll
    for (int n = 0; n < 4; ++n) {
      int col = bx*128 + wc*64 + n*16 + (lane&15);
      float bv = bias[col];
      #pragma unroll
      for (int rr = 0; rr < 4; ++rr) {
        int row = by*128 + wr*64 + m*16 + (lane>>4)*4 + rr;
        out[(size_t)row*1024 + col] = acc[m][n][rr] + bv;
      }
    }
}

// ---------------- per-row attention, wave-per-row (4 rows/block, no barriers/LDS) ----------------
__global__ __launch_bounds__(256) void k_attn(const float* __restrict__ OVL,
                                              const float* __restrict__ HID,
                                              const float* __restrict__ n2a,
                                              const float* __restrict__ n2b,
                                              const float* __restrict__ VG,
                                              const float* __restrict__ pb1,
                                              const float* __restrict__ pw2,
                                              const float* __restrict__ pb2,
                                              const float* __restrict__ gb,
                                              _Float16* __restrict__ WH,
                                              _Float16* __restrict__ WL) {
  const int wid = threadIdx.x >> 6;
  const int lane = threadIdx.x & 63;
  const int r = blockIdx.x * 4 + wid;          // one wave per row
  const int h = lane >> 3;                     // head 0..7 (8 lanes each)
  const int sub = lane & 7;                    // 8 s-values per lane
  const float* ovp = OVL + (size_t)r*512 + h*64 + sub*8;
  float4 o0 = *(const float4*)ovp;
  float4 o1 = *(const float4*)(ovp + 4);
  float ov[8] = {o0.x, o0.y, o0.z, o0.w, o1.x, o1.y, o1.z, o1.w};
  float z = 0.f;
  #pragma unroll
  for (int t = 0; t < 2; ++t) {
    int kk = sub*2 + t;
    float x = HID[(size_t)r*128 + h*16 + kk] + pb1[h*16 + kk];
    float sg = 1.f / (1.f + expf(-x));
    z += x * sg * pw2[h*16 + kk];
  }
  z += __shfl_xor(z, 1); z += __shfl_xor(z, 2); z += __shfl_xor(z, 4);
  z += pb2[h];
  float p = 0.95f / (1.f + expf(-z));
  float nn = n2a[(size_t)r*8 + h] + n2b[(size_t)r*8 + h];
  float inv_n2 = 1.f / fmaxf(nn, 1e-24f);
  float base = (1.f - p) * 0.0078125f;   // (1-p)/128
  float rw[8];
  float rsum = 0.f;
  #pragma unroll
  for (int q = 0; q < 8; ++q) { rw[q] = p * (ov[q] * inv_n2) + base; rsum += rw[q]; }
  rsum += __shfl_xor(rsum, 1); rsum += __shfl_xor(rsum, 2); rsum += __shfl_xor(rsum, 4);
  float inv_den = 1.f / (rsum + 1e-8f);
  float a[8];
  #pragma unroll
  for (int q = 0; q < 8; ++q) a[q] = rw[q] * inv_den;
  float lg[8] = {0,0,0,0,0,0,0,0};
  const float* vgp = VG + (size_t)(h*64 + sub*8) * 8;
  #pragma unroll
  for (int q = 0; q < 8; ++q)
    #pragma unroll
    for (int g = 0; g < 8; ++g) lg[g] += a[q] * vgp[q*8 + g];
  #pragma unroll
  for (int off = 1; off < 64; off <<= 1)
    #pragma unroll
    for (int g = 0; g < 8; ++g) lg[g] += __shfl_xor(lg[g], off);
  float lt[8];
  #pragma unroll
  for (int g = 0; g < 8; ++g) lt[g] = lg[g] + gb[g];
  float mx = lt[0];
  #pragma unroll
  for (int g = 1; g < 8; ++g) mx = fmaxf(mx, lt[g]);
  float den = 0.f;
  #pragma unroll
  for (int g = 0; g < 8; ++g) den += expf(lt[g] - mx);
  float gate = expf(lt[h] - mx) / den;
  int mt = r >> 7, r8 = (r >> 4) & 7, r15 = r & 15;
  size_t basek = ((size_t)mt*16 + h*2 + (sub >> 2)) * 4096
               + (size_t)r8*512 + (size_t)(sub & 3)*128 + (size_t)r15*8;
  f16x8 hv, lv;
  #pragma unroll
  for (int q = 0; q < 8; ++q) {
    _Float16 hi, lo;
    split16(a[q] * gate, hi, lo);
    hv[q] = hi; lv[q] = lo;
  }
  *(f16x8*)(WH + basek) = hv;
  *(f16x8*)(WL + basek) = lv;
}

extern "C" void kernel_launch(void* const* d_in, const int* in_sizes, int n_in,
                              void* d_out, int out_size, void* d_ws, size_t ws_size,
                              hipStream_t stream) {
  const float* h_   = (const float*)d_in[0];
  const float* Wr   = (const float*)d_in[1];
  const float* Wi   = (const float*)d_in[2];
  const float* pw1  = (const float*)d_in[3];
  const float* pb1  = (const float*)d_in[4];
  const float* pw2  = (const float*)d_in[5];
  const float* pb2  = (const float*)d_in[6];
  const float* mr   = (const float*)d_in[7];
  const float* mi   = (const float*)d_in[8];
  const float* vals = (const float*)d_in[9];
  const float* gw   = (const float*)d_in[10];
  const float* gb   = (const float*)d_in[11];
  const float* ow   = (const float*)d_in[12];
  const float* ob   = (const float*)d_in[13];

  if (ws_size < WS_FLOATS * sizeof(float)) return;

  float* ws   = (float*)d_ws;
  float* OVL  = ws + OFF_OVL;
  float* HID  = ws + OFF_HID;
  float* n2a  = ws + OFF_N2;
  float* n2b  = ws + OFF_MRE;
  float* VG   = ws + OFF_VG;
  _Float16* VWH = (_Float16*)(ws + OFF_VWH);
  _Float16* VWL = (_Float16*)(ws + OFF_VWL);
  _Float16* BH  = (_Float16*)(ws + OFF_BH);
  _Float16* BL  = (_Float16*)(ws + OFF_BL);
  _Float16* AH  = (_Float16*)(ws + OFF_AH);
  _Float16* AL  = (_Float16*)(ws + OFF_AL);
  _Float16* WH  = (_Float16*)(ws + OFF_AH);  // alias: A dead after k_qmm
  _Float16* WL  = (_Float16*)(ws + OFF_AL);

  k_prep_all<<<6080, 256, 0, stream>>>(h_, Wr, Wi, pw1, mr, mi, vals, gw, ow,
                                       VG, BH, BL, VWH, VWL, AH, AL);
  k_qmm<<<2176, 256, 0, stream>>>(AH, AL, BH, BL, OVL, HID, n2a, n2b);
  k_attn<<<4096, 256, 0, stream>>>(OVL, HID, n2a, n2b, VG, pb1, pw2, pb2, gb, WH, WL);
  k_fin<<<1024, 256, 0, stream>>>(WH, WL, VWH, VWL, ob, (float*)d_out);
}

// Round 21
// 326.692 us; speedup vs baseline: 1.2974x; 1.0950x over previous
//
#include <hip/hip_runtime.h>
#include <hip/hip_bf16.h>
#include <math.h>

#define ROWS 16384   // B*N = 8*2048

typedef _Float16 f16x8 __attribute__((ext_vector_type(8)));
typedef float f32x4 __attribute__((ext_vector_type(4)));

// ---- workspace offsets (floats); total identical to proven 31,330,304 ----
static const size_t OFF_OVL = 0;            // 16384*512 fp32 overlap
static const size_t OFF_HID = 8388608;      // 16384*128 fp32
static const size_t OFF_N2  = 10485760;     // 16384*8  (n2a)
static const size_t OFF_VG  = 10616832;     // 512*8
static const size_t OFF_MRE = 10620928;     // 65536 (n2b)
static const size_t OFF_MIM = 10686464;     // 65536 (unused)
static const size_t OFF_VWH = 10752000;     // 512*1024 f16 = 262144 fl
static const size_t OFF_VWL = 11014144;     // 262144 fl
static const size_t OFF_BH  = 11276288;     // 1024*3200 f16 = 1638400 fl
static const size_t OFF_BL  = 12914688;     // 1638400 fl
static const size_t OFF_AH  = 14553088;     // 16384*1024 f16 = 8388608 fl; late: WH alias
static const size_t OFF_AL  = 22941696;     // 8388608 fl; late: WL alias
static const size_t WS_FLOATS = 31330304;   // 125.32 MB

__device__ __forceinline__ void gload_lds16(const void* g, void* l) {
  __builtin_amdgcn_global_load_lds((const __attribute__((address_space(1))) void*)g,
                                   (__attribute__((address_space(3))) void*)l, 16, 0, 0);
}

__device__ __forceinline__ void split16(float v, _Float16& hi, _Float16& lo) {
  _Float16 h = (_Float16)v;
  hi = h;
  lo = (_Float16)(v - (float)h);
}

// ---------------- merged prep, long-first order: gemm64(0-127) | aov16(128-383) | vg(384-895) | b16(896-1983) | convA(1984-6079) ----------------
__global__ __launch_bounds__(256) void k_prep_all(const float* __restrict__ h_,
                                                  const float* __restrict__ Wr,
                                                  const float* __restrict__ Wi,
                                                  const float* __restrict__ pw1,
                                                  const float* __restrict__ mr,
                                                  const float* __restrict__ mi,
                                                  const float* __restrict__ vals,
                                                  const float* __restrict__ gw,
                                                  const float* __restrict__ ow,
                                                  float* __restrict__ VG,
                                                  _Float16* __restrict__ BH,
                                                  _Float16* __restrict__ BL,
                                                  _Float16* __restrict__ VWH,
                                                  _Float16* __restrict__ VWL,
                                                  _Float16* __restrict__ AH,
                                                  _Float16* __restrict__ AL) {
  __shared__ __align__(16) char pbuf[33024];
  const int b = blockIdx.x;
  const int tid = threadIdx.x;

  if (b < 128) {
    // ---- gemm64 (BK=32): VW = vals(512x1024) @ ow(1024x1024) -> VWH/VWL fragment tiles ----
    int sub = b;                        // 0..127
    int col0 = (sub & 15) << 6, row0 = (sub >> 4) << 6;
    float (*As)[64] = (float(*)[64])pbuf;            // [32][64]
    float (*Bs)[64] = (float(*)[64])(pbuf + 8192);   // [32][64]
    int tm = tid >> 4, tn = tid & 15;
    float acc[4][4];
    #pragma unroll
    for (int i = 0; i < 4; ++i)
      #pragma unroll
      for (int j = 0; j < 4; ++j) acc[i][j] = 0.f;
    int ar = tid >> 2, ak = (tid & 3) << 3;          // ak 0,8,16,24
    int bkr = tid >> 4, bc = (tid & 15) << 2;
    for (int kt = 0; kt < 1024; kt += 32) {
      float4 a0 = *(const float4*)(vals + (size_t)(row0 + ar)*1024 + kt + ak);
      float4 a1 = *(const float4*)(vals + (size_t)(row0 + ar)*1024 + kt + ak + 4);
      float4 b0 = *(const float4*)(ow + (size_t)(kt + bkr)*1024 + col0 + bc);
      float4 b1 = *(const float4*)(ow + (size_t)(kt + 16 + bkr)*1024 + col0 + bc);
      __syncthreads();
      As[ak+0][ar] = a0.x; As[ak+1][ar] = a0.y; As[ak+2][ar] = a0.z; As[ak+3][ar] = a0.w;
      As[ak+4][ar] = a1.x; As[ak+5][ar] = a1.y; As[ak+6][ar] = a1.z; As[ak+7][ar] = a1.w;
      *(float4*)&Bs[bkr][bc]      = b0;
      *(float4*)&Bs[bkr + 16][bc] = b1;
      __syncthreads();
      #pragma unroll
      for (int k = 0; k < 32; ++k) {
        float af[4], bf[4];
        *(float4*)&af[0] = *(const float4*)&As[k][tm << 2];
        *(float4*)&bf[0] = *(const float4*)&Bs[k][tn << 2];
        #pragma unroll
        for (int i = 0; i < 4; ++i)
          #pragma unroll
          for (int j = 0; j < 4; ++j) acc[i][j] += af[i] * bf[j];
      }
    }
    #pragma unroll
    for (int i = 0; i < 4; ++i) {
      int row = row0 + (tm << 2) + i;            // k-dim 0..511
      int ktl = row >> 5, kg = (row >> 3) & 3, jj = row & 7;
      #pragma unroll
      for (int j = 0; j < 4; ++j) {
        int col = col0 + (tn << 2) + j;          // 0..1023
        int nt = col >> 7, c8 = (col >> 4) & 7, c15 = col & 15;
        size_t base = ((size_t)nt*16 + ktl)*4096 + c8*512 + kg*128 + c15*8 + jj;
        _Float16 hi, lo; split16(acc[i][j], hi, lo);
        VWH[base] = hi; VWL[base] = lo;
      }
    }

  } else if (b < 384) {
    // ---- prep_aov16: normalize mr/mi in-LDS -> Aov -> BH/BL (nt 16..23) ----
    int bid = b - 128;             // h(8) x kt64(16) x shalf(2)
    int h   = bid >> 5;
    int kt64 = (bid >> 1) & 15;
    int sh  = bid & 1;
    float (*sRe)[129] = (float(*)[129])pbuf;
    float (*sIm)[129] = (float(*)[129])(pbuf + 16512);
    int s0 = sh * 32;
    for (int i = tid; i < 32 * 32; i += 256) {
      int s = i >> 5; int e4 = (i & 31) << 2;
      *(float4*)&sRe[s][e4] = *(const float4*)(mr + ((size_t)(h*64 + s0 + s)*128 + e4));
      *(float4*)&sIm[s][e4] = *(const float4*)(mi + ((size_t)(h*64 + s0 + s)*128 + e4));
    }
    __syncthreads();
    {
      int row = tid >> 3, part = tid & 7;
      float ss = 0.f;
      #pragma unroll
      for (int e = 0; e < 16; ++e) {
        float a = sRe[row][part*16 + e], bb = sIm[row][part*16 + e];
        ss += a*a + bb*bb;
      }
      ss += __shfl_xor(ss, 1); ss += __shfl_xor(ss, 2); ss += __shfl_xor(ss, 4);
      float inv = 1.f / fmaxf(sqrtf(ss), 1e-12f);
      #pragma unroll
      for (int e = 0; e < 16; ++e) {
        sRe[row][part*16 + e] *= inv;
        sIm[row][part*16 + e] *= inv;
      }
    }
    __syncthreads();
    int kq = tid >> 5;
    int s  = tid & 31;
    int kbase = kt64*64 + kq*8;
    float aR[8] = {0,0,0,0,0,0,0,0}, aI[8] = {0,0,0,0,0,0,0,0};
    for (int e0 = 0; e0 < 128; e0 += 4) {
      float4 mre = *(float4*)&sRe[s][e0];
      float4 mim = *(float4*)&sIm[s][e0];
      #pragma unroll
      for (int j = 0; j < 8; ++j) {
        const float4 wr = *(const float4*)(Wr + ((size_t)(h*1024 + kbase + j))*128 + e0);
        const float4 wi = *(const float4*)(Wi + ((size_t)(h*1024 + kbase + j))*128 + e0);
        aR[j] += wr.x*mre.x + wr.y*mre.y + wr.z*mre.z + wr.w*mre.w
               + wi.x*mim.x + wi.y*mim.y + wi.z*mim.z + wi.w*mim.w;
        aI[j] += wi.x*mre.x + wi.y*mre.y + wi.z*mre.z + wi.w*mre.w
               - (wr.x*mim.x + wr.y*mim.y + wr.z*mim.z + wr.w*mim.w);
      }
    }
    int kt32 = kbase >> 5;
    int kg   = (kbase >> 3) & 3;
    int coln = s0 + s;
    size_t baseR = ((size_t)(16 + h)*32 + kt32)*4096 + (size_t)(coln >> 4)*512 + kg*128 + (coln & 15)*8;
    size_t baseI = baseR + 4*512;
    f16x8 hR, lR, hI, lI;
    #pragma unroll
    for (int j = 0; j < 8; ++j) {
      _Float16 hi, lo;
      split16(aR[j], hi, lo); hR[j] = hi; lR[j] = lo;
      split16(aI[j], hi, lo); hI[j] = hi; lI[j] = lo;
    }
    *(f16x8*)(BH + baseR) = hR; *(f16x8*)(BL + baseR) = lR;
    *(f16x8*)(BH + baseI) = hI; *(f16x8*)(BL + baseI) = lI;

  } else if (b < 896) {
    // ---- prep_vg: VG[h,s,g] ----
    int hs = b - 384;
    int h  = hs >> 6;
    float acc[8] = {0,0,0,0,0,0,0,0};
    for (int dd = tid; dd < 1024; dd += 256) {
      float v = vals[(size_t)hs*1024 + dd];
      const float* g = gw + (size_t)(h*1024 + dd)*8;
      #pragma unroll
      for (int q = 0; q < 8; ++q) acc[q] += v * g[q];
    }
    #pragma unroll
    for (int off = 1; off < 64; off <<= 1)
      #pragma unroll
      for (int q = 0; q < 8; ++q) acc[q] += __shfl_xor(acc[q], off);
    float* red = (float*)pbuf;   // [4][8]
    if ((tid & 63) == 0) {
      #pragma unroll
      for (int q = 0; q < 8; ++q) red[(tid >> 6)*8 + q] = acc[q];
    }
    __syncthreads();
    if (tid < 8) VG[(size_t)hs*8 + tid] = red[tid] + red[8 + tid] + red[16 + tid] + red[24 + tid];

  } else if (b < 1984) {
    // ---- prep_b16: Wr/Wi/pw1 -> BH/BL fragment tiles ----
    int g = (b - 896) * 256 + tid;   // 128*2176 = 278528 total
    int c  = g % 2176;
    int k0 = g / 2176;
    float v[8];
    if (c < 1024) {
      int h = c >> 7, e = c & 127;
      const float* p = Wr + ((size_t)(h << 10) + k0*8) * 128 + e;
      #pragma unroll
      for (int j = 0; j < 8; ++j) v[j] = p[(size_t)j*128];
    } else if (c < 2048) {
      int c2 = c - 1024; int h = c2 >> 7, e = c2 & 127;
      const float* p = Wi + ((size_t)(h << 10) + k0*8) * 128 + e;
      #pragma unroll
      for (int j = 0; j < 8; ++j) v[j] = p[(size_t)j*128];
    } else {
      int q = c - 2048; int h = q >> 4, kk = q & 15;
      const float* p = pw1 + ((size_t)(h << 10) + k0*8) * 16 + kk;
      #pragma unroll
      for (int j = 0; j < 8; ++j) v[j] = p[(size_t)j*16];
    }
    int Bcol = (c < 2048) ? c : 3072 + (c - 2048);
    int nt = Bcol >> 7, c8 = (Bcol >> 4) & 7, c15 = Bcol & 15;
    int kt = k0 >> 2, kg = k0 & 3;
    size_t base = ((size_t)nt*32 + kt)*4096 + c8*512 + kg*128 + c15*8;
    f16x8 hv, lv;
    #pragma unroll
    for (int j = 0; j < 8; ++j) { _Float16 hi, lo; split16(v[j], hi, lo); hv[j] = hi; lv[j] = lo; }
    *(f16x8*)(BH + base) = hv;
    *(f16x8*)(BL + base) = lv;

  } else {
    // ---- convA: h row-major -> AH/AL fragment tiles ----
    int cb = b - 1984;                  // 0..4095
    int mt = cb >> 5, kt = cb & 31;
    size_t tbase = (size_t)cb * 4096;
    #pragma unroll
    for (int it = 0; it < 2; ++it) {
      int p = it*256 + tid;            // 0..511 = r8*64 + kg*16 + r15
      int r8 = p >> 6, kg = (p >> 4) & 3, r15 = p & 15;
      int row = mt*128 + r8*16 + r15;
      int col = kt*32 + kg*8;
      const float* s = h_ + (size_t)row*1024 + col;
      float4 v0 = *(const float4*)s;
      float4 v1 = *(const float4*)(s + 4);
      float vv[8] = {v0.x, v0.y, v0.z, v0.w, v1.x, v1.y, v1.z, v1.w};
      f16x8 hv, lv;
      #pragma unroll
      for (int j = 0; j < 8; ++j) { _Float16 hi, lo; split16(vv[j], hi, lo); hv[j] = hi; lv[j] = lo; }
      size_t i = tbase + (size_t)r8*512 + kg*128 + r15*8;
      *(f16x8*)(AH + i) = hv;
      *(f16x8*)(AL + i) = lv;
    }
  }
}

// ---------------- merged MFMA GEMM: qval-OV (0..1023) | qnorm256 (1024..2047) | HID hi-only (2048..2175) ----------------
__global__ __launch_bounds__(256) void k_qmm(const _Float16* __restrict__ Ah,
                                             const _Float16* __restrict__ Al,
                                             const _Float16* __restrict__ Bh,
                                             const _Float16* __restrict__ Bl,
                                             float* __restrict__ OVL,
                                             float* __restrict__ HID,
                                             float* __restrict__ n2a,
                                             float* __restrict__ n2b) {
  __shared__ __align__(16) char smem[65536];
  const int gid = blockIdx.x;
  const int tid = threadIdx.x;
  const int wid = tid >> 6, lane = tid & 63;
  const int wr = wid >> 1, wc = wid & 1;

  if (gid < 1024) {
    // ======== qval OV: 3-term, 128x128, 2-barrier double-buffered (proven) ========
    const int id = gid;
    const int by = (id & 7) * 16 + ((id >> 3) & 15);
    const int bx = id >> 7;                      // 0..7
    f32x4 acc[4][4];
    #pragma unroll
    for (int i = 0; i < 4; ++i)
      #pragma unroll
      for (int j = 0; j < 4; ++j) acc[i][j] = (f32x4){0.f,0.f,0.f,0.f};

    const char* pAh = (const char*)Ah + (size_t)by*32*8192;
    const char* pAl = (const char*)Al + (size_t)by*32*8192;
    const char* pBh = (const char*)Bh + (size_t)(16 + bx)*32*8192;
    const char* pBl = (const char*)Bl + (size_t)(16 + bx)*32*8192;
    const char* mysrc = (wid == 0) ? pAh : (wid == 1) ? pAl : (wid == 2) ? pBh : pBl;

    auto stage = [&](int b, int kt) {
      const char* s = mysrc + (size_t)kt*8192 + lane*16;
      char* d = smem + b*32768 + wid*8192;
      #pragma unroll
      for (int q = 0; q < 8; ++q)
        gload_lds16(s + q*1024, d + q*1024);
    };

    stage(0, 0);
    asm volatile("s_waitcnt vmcnt(0)" ::: "memory");
    __builtin_amdgcn_s_barrier();
    int cur = 0;
    for (int kt = 0; kt < 32; ++kt) {
      if (kt < 31) stage(cur ^ 1, kt + 1);
      const char* base = smem + cur*32768;
      const char* cAh = base;
      const char* cAl = base + 8192;
      const char* cBh = base + 16384;
      const char* cBl = base + 24576;
      f16x8 a_h[4], a_l[4], b_h[4], b_l[4];
      #pragma unroll
      for (int m = 0; m < 4; ++m) { a_h[m] = *(const f16x8*)(cAh + wr*4096 + m*1024 + lane*16);
                                    a_l[m] = *(const f16x8*)(cAl + wr*4096 + m*1024 + lane*16); }
      #pragma unroll
      for (int n = 0; n < 4; ++n) { b_h[n] = *(const f16x8*)(cBh + wc*4096 + n*1024 + lane*16);
                                    b_l[n] = *(const f16x8*)(cBl + wc*4096 + n*1024 + lane*16); }
      #pragma unroll
      for (int m = 0; m < 4; ++m)
        #pragma unroll
        for (int n = 0; n < 4; ++n) {
          acc[m][n] = __builtin_amdgcn_mfma_f32_16x16x32_f16(a_h[m], b_h[n], acc[m][n], 0, 0, 0);
          acc[m][n] = __builtin_amdgcn_mfma_f32_16x16x32_f16(a_l[m], b_h[n], acc[m][n], 0, 0, 0);
          acc[m][n] = __builtin_amdgcn_mfma_f32_16x16x32_f16(a_h[m], b_l[n], acc[m][n], 0, 0, 0);
        }
      if (kt < 31) {
        asm volatile("s_waitcnt vmcnt(0)" ::: "memory");
        __builtin_amdgcn_s_barrier();
      }
      cur ^= 1;
    }
    __syncthreads();   // all waves done with LDS buffers before epilogue reuse

    float* sOv = (float*)smem;   // [128][68]
    if (wc == 0) {
      #pragma unroll
      for (int m = 0; m < 4; ++m)
        #pragma unroll
        for (int n = 0; n < 4; ++n)
          #pragma unroll
          for (int rr = 0; rr < 4; ++rr) {
            int r128 = wr*64 + m*16 + (lane>>4)*4 + rr;
            int s = n*16 + (lane&15);
            sOv[r128*68 + s] = acc[m][n][rr]*acc[m][n][rr];
          }
    }
    __syncthreads();
    if (wc == 1) {
      #pragma unroll
      for (int m = 0; m < 4; ++m)
        #pragma unroll
        for (int n = 0; n < 4; ++n)
          #pragma unroll
          for (int rr = 0; rr < 4; ++rr) {
            int r128 = wr*64 + m*16 + (lane>>4)*4 + rr;
            int s = n*16 + (lane&15);
            float v = sOv[r128*68 + s] + acc[m][n][rr]*acc[m][n][rr];
            int row = by*128 + r128;
            OVL[(size_t)row*512 + bx*64 + s] = v;
          }
    }

  } else if (gid < 2048) {
    // ======== qnorm256: hi-only, 128x256, counted-vmcnt pipeline; wave owns one head ========
    const int id = gid - 1024;
    const int by = (id & 7) * 16 + ((id >> 3) & 15);
    const int bx = id >> 7;                      // 0..7
    const char* gA  = (const char*)Ah + (size_t)by * 32 * 8192;
    const char* gB0 = (const char*)Bh + (size_t)(2*bx)     * 32 * 8192;
    const char* gB1 = (const char*)Bh + (size_t)(2*bx + 1) * 32 * 8192;

    f32x4 acc[4][8];
    #pragma unroll
    for (int i = 0; i < 4; ++i)
      #pragma unroll
      for (int j = 0; j < 8; ++j) acc[i][j] = (f32x4){0.f,0.f,0.f,0.f};

    auto stage = [&](int b, int kt) {
      char* dbuf = smem + b * 24576;
      #pragma unroll
      for (int q = 0; q < 6; ++q) {
        int c = wid * 6 + q;                     // 0..23 (wave-uniform)
        const char* s;
        if (c < 8)       s = gA  + (size_t)kt*8192 + c*1024;
        else if (c < 16) s = gB0 + (size_t)kt*8192 + (c-8)*1024;
        else             s = gB1 + (size_t)kt*8192 + (c-16)*1024;
        gload_lds16(s + lane*16, dbuf + c*1024);
      }
    };

    stage(0, 0);
    stage(1, 1);
    asm volatile("s_waitcnt vmcnt(6)" ::: "memory");
    __builtin_amdgcn_s_barrier();
    for (int kt = 0; kt < 32; ++kt) {
      const char* cb = smem + (kt & 1) * 24576;
      const char* bb = cb + 8192 + wc * 8192;
      f16x8 a[4], b[8];
      #pragma unroll
      for (int m = 0; m < 4; ++m) a[m] = *(const f16x8*)(cb + wr*4096 + m*1024 + lane*16);
      #pragma unroll
      for (int n = 0; n < 8; ++n) b[n] = *(const f16x8*)(bb + n*1024 + lane*16);
      asm volatile("s_waitcnt lgkmcnt(0)" ::: "memory");
      __builtin_amdgcn_s_barrier();
      if (kt < 30) stage(kt & 1, kt + 2);
      #pragma unroll
      for (int m = 0; m < 4; ++m)
        #pragma unroll
        for (int n = 0; n < 8; ++n)
          acc[m][n] = __builtin_amdgcn_mfma_f32_16x16x32_f16(a[m], b[n], acc[m][n], 0, 0, 0);
      if (kt < 31) {
        if (kt < 30) asm volatile("s_waitcnt vmcnt(6)" ::: "memory");
        else         asm volatile("s_waitcnt vmcnt(0)" ::: "memory");
        __builtin_amdgcn_s_barrier();
      }
    }

    const int nt = 2*bx + wc;
    float* dst = (nt < 8) ? n2a : n2b;
    const int head = nt & 7;
    #pragma unroll
    for (int m = 0; m < 4; ++m)
      #pragma unroll
      for (int rr = 0; rr < 4; ++rr) {
        float rs = 0.f;
        #pragma unroll
        for (int n = 0; n < 8; ++n) rs += acc[m][n][rr] * acc[m][n][rr];
        rs += __shfl_xor(rs, 1); rs += __shfl_xor(rs, 2);
        rs += __shfl_xor(rs, 4); rs += __shfl_xor(rs, 8);
        if ((lane & 15) == 0) {
          int row = by*128 + wr*64 + m*16 + (lane >> 4)*4 + rr;
          dst[(size_t)row*8 + head] = rs;
        }
      }

  } else {
    // ======== HID: hi-only 1-term, 128x128, 2-barrier double-buffered (short tail tiles) ========
    const int id = gid - 2048;                   // 0..127
    const int by = (id & 7) * 16 + ((id >> 3) & 15);
    const char* pAh = (const char*)Ah + (size_t)by*32*8192;
    const char* pBh = (const char*)Bh + (size_t)24*32*8192;   // nt=24 = pw1 panel
    f32x4 acc[4][4];
    #pragma unroll
    for (int i = 0; i < 4; ++i)
      #pragma unroll
      for (int j = 0; j < 4; ++j) acc[i][j] = (f32x4){0.f,0.f,0.f,0.f};

    auto stage = [&](int b, int kt) {
      char* dbuf = smem + b*16384;
      #pragma unroll
      for (int q = 0; q < 4; ++q) {
        int c = wid*4 + q;                       // 0..15 (wave-uniform)
        const char* s = (c < 8) ? pAh + (size_t)kt*8192 + c*1024
                                : pBh + (size_t)kt*8192 + (c-8)*1024;
        gload_lds16(s + lane*16, dbuf + c*1024);
      }
    };

    stage(0, 0);
    asm volatile("s_waitcnt vmcnt(0)" ::: "memory");
    __builtin_amdgcn_s_barrier();
    int cur = 0;
    for (int kt = 0; kt < 32; ++kt) {
      if (kt < 31) stage(cur ^ 1, kt + 1);
      const char* cAh = smem + cur*16384;
      const char* cBh = cAh + 8192;
      f16x8 a_h[4], b_h[4];
      #pragma unroll
      for (int m = 0; m < 4; ++m) a_h[m] = *(const f16x8*)(cAh + wr*4096 + m*1024 + lane*16);
      #pragma unroll
      for (int n = 0; n < 4; ++n) b_h[n] = *(const f16x8*)(cBh + wc*4096 + n*1024 + lane*16);
      #pragma unroll
      for (int m = 0; m < 4; ++m)
        #pragma unroll
        for (int n = 0; n < 4; ++n)
          acc[m][n] = __builtin_amdgcn_mfma_f32_16x16x32_f16(a_h[m], b_h[n], acc[m][n], 0, 0, 0);
      if (kt < 31) {
        asm volatile("s_waitcnt vmcnt(0)" ::: "memory");
        __builtin_amdgcn_s_barrier();
      }
      cur ^= 1;
    }
    #pragma unroll
    for (int m = 0; m < 4; ++m)
      #pragma unroll
      for (int n = 0; n < 4; ++n)
        #pragma unroll
        for (int rr = 0; rr < 4; ++rr) {
          int row = by*128 + wr*64 + m*16 + (lane>>4)*4 + rr;
          int col = wc*64 + n*16 + (lane&15);
          HID[(size_t)row*128 + col] = acc[m][n][rr];
        }
  }
}

// ---------------- final MFMA GEMM: counted-vmcnt pipeline; out = wattn @ VW + out_b ----------------
__global__ __launch_bounds__(256) void k_fin(const _Float16* __restrict__ Ahh,
                                             const _Float16* __restrict__ Alo,
                                             const _Float16* __restrict__ Bhh,
                                             const _Float16* __restrict__ Blo,
                                             const float* __restrict__ bias,
                                             float* __restrict__ out) {
  __shared__ __align__(16) char smem[65536];
  const int id = blockIdx.x;                   // 1024: XCD-partitioned decode
  const int by = (id & 7) * 16 + ((id >> 3) & 15);   // 0..127
  const int bx = id >> 7;                      // 0..7
  const int tid = threadIdx.x;
  const int wid = tid >> 6, lane = tid & 63;
  const int wr = wid >> 1, wc = wid & 1;
  f32x4 acc[4][4];
  #pragma unroll
  for (int i = 0; i < 4; ++i)
    #pragma unroll
    for (int j = 0; j < 4; ++j) acc[i][j] = (f32x4){0.f,0.f,0.f,0.f};
  const char* pAh = (const char*)Ahh + (size_t)by*16*8192;
  const char* pAl = (const char*)Alo + (size_t)by*16*8192;
  const char* pBh = (const char*)Bhh + (size_t)bx*16*8192;
  const char* pBl = (const char*)Blo + (size_t)bx*16*8192;
  const char* mysrc = (wid == 0) ? pAh : (wid == 1) ? pAl : (wid == 2) ? pBh : pBl;

  auto stage = [&](int b, int kt) {
    const char* s = mysrc + (size_t)kt*8192 + lane*16;
    char* d = smem + b*32768 + wid*8192;
    #pragma unroll
    for (int q = 0; q < 8; ++q)
      gload_lds16(s + q*1024, d + q*1024);
  };

  stage(0, 0);
  stage(1, 1);
  asm volatile("s_waitcnt vmcnt(8)" ::: "memory");
  __builtin_amdgcn_s_barrier();
  for (int kt = 0; kt < 16; ++kt) {
    const char* base = smem + (kt & 1)*32768;
    const char* cAh = base;
    const char* cAl = base + 8192;
    const char* cBh = base + 16384;
    const char* cBl = base + 24576;
    f16x8 a_h[4], a_l[4], b_h[4], b_l[4];
    #pragma unroll
    for (int m = 0; m < 4; ++m) { a_h[m] = *(const f16x8*)(cAh + wr*4096 + m*1024 + lane*16);
                                  a_l[m] = *(const f16x8*)(cAl + wr*4096 + m*1024 + lane*16); }
    #pragma unroll
    for (int n = 0; n < 4; ++n) { b_h[n] = *(const f16x8*)(cBh + wc*4096 + n*1024 + lane*16);
                                  b_l[n] = *(const f16x8*)(cBl + wc*4096 + n*1024 + lane*16); }
    asm volatile("s_waitcnt lgkmcnt(0)" ::: "memory");
    __builtin_amdgcn_s_barrier();
    if (kt < 14) stage(kt & 1, kt + 2);
    #pragma unroll
    for (int m = 0; m < 4; ++m)
      #pragma unroll
      for (int n = 0; n < 4; ++n) {
        acc[m][n] = __builtin_amdgcn_mfma_f32_16x16x32_f16(a_h[m], b_h[n], acc[m][n], 0, 0, 0);
        acc[m][n] = __builtin_amdgcn_mfma_f32_16x16x32_f16(a_l[m], b_h[n], acc[m][n], 0, 0, 0);
        acc[m][n] = __builtin_amdgcn_mfma_f32_16x16x32_f16(a_h[m], b_l[n], acc[m][n], 0, 0, 0);
      }
    if (kt < 15) {
      if (kt < 14) asm volatile("s_waitcnt vmcnt(8)" ::: "memory");
      else         asm volatile("s_waitcnt vmcnt(0)" ::: "memory");
      __builtin_amdgcn_s_barrier();
    }
  }
  #pragma unroll
  for (int m = 0; m < 4; ++m)
    #pragma unroll
    for (int n = 0; n < 4; ++n) {
      int col = bx*128 + wc*64 + n*16 + (lane&15);
      float bv = bias[col];
      #pragma unroll
      for (int rr = 0; rr < 4; ++rr) {
        int row = by*128 + wr*64 + m*16 + (lane>>4)*4 + rr;
        out[(size_t)row*1024 + col] = acc[m][n][rr] + bv;
      }
    }
}

// ---------------- per-row attention, wave-per-row (4 rows/block, no barriers/LDS) ----------------
__global__ __launch_bounds__(256) void k_attn(const float* __restrict__ OVL,
                                              const float* __restrict__ HID,
                                              const float* __restrict__ n2a,
                                              const float* __restrict__ n2b,
                                              const float* __restrict__ VG,
                                              const float* __restrict__ pb1,
                                              const float* __restrict__ pw2,
                                              const float* __restrict__ pb2,
                                              const float* __restrict__ gb,
                                              _Float16* __restrict__ WH,
                                              _Float16* __restrict__ WL) {
  const int wid = threadIdx.x >> 6;
  const int lane = threadIdx.x & 63;
  const int r = blockIdx.x * 4 + wid;          // one wave per row
  const int h = lane >> 3;                     // head 0..7 (8 lanes each)
  const int sub = lane & 7;                    // 8 s-values per lane
  const float* ovp = OVL + (size_t)r*512 + h*64 + sub*8;
  float4 o0 = *(const float4*)ovp;
  float4 o1 = *(const float4*)(ovp + 4);
  float ov[8] = {o0.x, o0.y, o0.z, o0.w, o1.x, o1.y, o1.z, o1.w};
  float z = 0.f;
  #pragma unroll
  for (int t = 0; t < 2; ++t) {
    int kk = sub*2 + t;
    float x = HID[(size_t)r*128 + h*16 + kk] + pb1[h*16 + kk];
    float sg = 1.f / (1.f + expf(-x));
    z += x * sg * pw2[h*16 + kk];
  }
  z += __shfl_xor(z, 1); z += __shfl_xor(z, 2); z += __shfl_xor(z, 4);
  z += pb2[h];
  float p = 0.95f / (1.f + expf(-z));
  float nn = n2a[(size_t)r*8 + h] + n2b[(size_t)r*8 + h];
  float inv_n2 = 1.f / fmaxf(nn, 1e-24f);
  float base = (1.f - p) * 0.0078125f;   // (1-p)/128
  float rw[8];
  float rsum = 0.f;
  #pragma unroll
  for (int q = 0; q < 8; ++q) { rw[q] = p * (ov[q] * inv_n2) + base; rsum += rw[q]; }
  rsum += __shfl_xor(rsum, 1); rsum += __shfl_xor(rsum, 2); rsum += __shfl_xor(rsum, 4);
  float inv_den = 1.f / (rsum + 1e-8f);
  float a[8];
  #pragma unroll
  for (int q = 0; q < 8; ++q) a[q] = rw[q] * inv_den;
  float lg[8] = {0,0,0,0,0,0,0,0};
  const float* vgp = VG + (size_t)(h*64 + sub*8) * 8;
  #pragma unroll
  for (int q = 0; q < 8; ++q)
    #pragma unroll
    for (int g = 0; g < 8; ++g) lg[g] += a[q] * vgp[q*8 + g];
  #pragma unroll
  for (int off = 1; off < 64; off <<= 1)
    #pragma unroll
    for (int g = 0; g < 8; ++g) lg[g] += __shfl_xor(lg[g], off);
  float lt[8];
  #pragma unroll
  for (int g = 0; g < 8; ++g) lt[g] = lg[g] + gb[g];
  float mx = lt[0];
  #pragma unroll
  for (int g = 1; g < 8; ++g) mx = fmaxf(mx, lt[g]);
  float den = 0.f;
  #pragma unroll
  for (int g = 0; g < 8; ++g) den += expf(lt[g] - mx);
  float gate = expf(lt[h] - mx) / den;
  int mt = r >> 7, r8 = (r >> 4) & 7, r15 = r & 15;
  size_t basek = ((size_t)mt*16 + h*2 + (sub >> 2)) * 4096
               + (size_t)r8*512 + (size_t)(sub & 3)*128 + (size_t)r15*8;
  f16x8 hv, lv;
  #pragma unroll
  for (int q = 0; q < 8; ++q) {
    _Float16 hi, lo;
    split16(a[q] * gate, hi, lo);
    hv[q] = hi; lv[q] = lo;
  }
  *(f16x8*)(WH + basek) = hv;
  *(f16x8*)(WL + basek) = lv;
}

extern "C" void kernel_launch(void* const* d_in, const int* in_sizes, int n_in,
                              void* d_out, int out_size, void* d_ws, size_t ws_size,
                              hipStream_t stream) {
  const float* h_   = (const float*)d_in[0];
  const float* Wr   = (const float*)d_in[1];
  const float* Wi   = (const float*)d_in[2];
  const float* pw1  = (const float*)d_in[3];
  const float* pb1  = (const float*)d_in[4];
  const float* pw2  = (const float*)d_in[5];
  const float* pb2  = (const float*)d_in[6];
  const float* mr   = (const float*)d_in[7];
  const float* mi   = (const float*)d_in[8];
  const float* vals = (const float*)d_in[9];
  const float* gw   = (const float*)d_in[10];
  const float* gb   = (const float*)d_in[11];
  const float* ow   = (const float*)d_in[12];
  const float* ob   = (const float*)d_in[13];

  if (ws_size < WS_FLOATS * sizeof(float)) return;

  float* ws   = (float*)d_ws;
  float* OVL  = ws + OFF_OVL;
  float* HID  = ws + OFF_HID;
  float* n2a  = ws + OFF_N2;
  float* n2b  = ws + OFF_MRE;
  float* VG   = ws + OFF_VG;
  _Float16* VWH = (_Float16*)(ws + OFF_VWH);
  _Float16* VWL = (_Float16*)(ws + OFF_VWL);
  _Float16* BH  = (_Float16*)(ws + OFF_BH);
  _Float16* BL  = (_Float16*)(ws + OFF_BL);
  _Float16* AH  = (_Float16*)(ws + OFF_AH);
  _Float16* AL  = (_Float16*)(ws + OFF_AL);
  _Float16* WH  = (_Float16*)(ws + OFF_AH);  // alias: A dead after k_qmm
  _Float16* WL  = (_Float16*)(ws + OFF_AL);

  k_prep_all<<<6080, 256, 0, stream>>>(h_, Wr, Wi, pw1, mr, mi, vals, gw, ow,
                                       VG, BH, BL, VWH, VWL, AH, AL);
  k_qmm<<<2176, 256, 0, stream>>>(AH, AL, BH, BL, OVL, HID, n2a, n2b);
  k_attn<<<4096, 256, 0, stream>>>(OVL, HID, n2a, n2b, VG, pb1, pw2, pb2, gb, WH, WL);
  k_fin<<<1024, 256, 0, stream>>>(WH, WL, VWH, VWL, ob, (float*)d_out);
}